// Round 8
// baseline (1759.496 us; speedup 1.0000x reference)
//
#include <hip/hip_runtime.h>
#include <cfloat>
#include <cstdint>

#define NB 32
#define NPTS 1024
#define KNN 20
#define RTOT (NB * NPTS)

typedef __attribute__((ext_vector_type(8))) short bf16x8;
typedef __attribute__((ext_vector_type(4))) float f32x4;

__device__ __forceinline__ float lrelu(float v) { return v >= 0.f ? v : 0.2f * v; }

// ---------------- transpose x (B,3,N) -> xT (B*N, 3) ----------------
__global__ void k_transpose_x(const float* __restrict__ x, float* __restrict__ xT) {
    int g = blockIdx.x * 256 + threadIdx.x;
    if (g >= NB * 3 * NPTS) return;
    int n = g % NPTS;
    int c = (g / NPTS) % 3;
    int b = g / (3 * NPTS);
    xT[((size_t)b * NPTS + n) * 3 + c] = x[g];
}

// ---------------- xx[r] = sum_c X[r,c]^2 ----------------
__global__ void k_xx(const float* __restrict__ X, int ldx, int C, float* __restrict__ xx) {
    int r = blockIdx.x * 256 + threadIdx.x;
    if (r >= RTOT) return;
    const float* p = X + (size_t)r * ldx;
    float s = 0.f;
    for (int c = 0; c < C; ++c) { float v = p[c]; s += v * v; }
    xx[r] = s;
}

// ---------------- 64x64 GEMM (small convs): H[r,o] = sum_k X[r,k]*W[o,k] ----------------
__global__ __launch_bounds__(256) void k_gemm_xwt(
    const float* __restrict__ X, int ldx, int K,
    const float* __restrict__ W,
    float* __restrict__ H, int ldh)
{
    __shared__ float As[16][68];
    __shared__ float Bs[16][68];
    int tid = threadIdx.x;
    int tx = tid & 15, ty = tid >> 4;
    int c0 = blockIdx.x * 64;
    int r0 = blockIdx.y * 64;
    float acc[4][4] = {};
    int lr = tid >> 4, lk = tid & 15;
    for (int k0 = 0; k0 < K; k0 += 16) {
#pragma unroll
        for (int i = 0; i < 4; ++i) {
            int row = lr + i * 16;
            int kk = k0 + lk;
            float av = 0.f, bv = 0.f;
            if (kk < K) {
                av = X[(size_t)(r0 + row) * ldx + kk];
                bv = W[(size_t)(c0 + row) * K + kk];
            }
            As[lk][row] = av;
            Bs[lk][row] = bv;
        }
        __syncthreads();
#pragma unroll
        for (int k = 0; k < 16; ++k) {
            float4 a4 = *(const float4*)&As[k][ty * 4];
            float4 b4 = *(const float4*)&Bs[k][tx * 4];
            float av[4] = {a4.x, a4.y, a4.z, a4.w};
            float bv[4] = {b4.x, b4.y, b4.z, b4.w};
#pragma unroll
            for (int i = 0; i < 4; ++i)
#pragma unroll
                for (int j = 0; j < 4; ++j)
                    acc[i][j] = fmaf(av[i], bv[j], acc[i][j]);
        }
        __syncthreads();
    }
#pragma unroll
    for (int i = 0; i < 4; ++i) {
        float4 v = make_float4(acc[i][0], acc[i][1], acc[i][2], acc[i][3]);
        *(float4*)&H[(size_t)(r0 + ty * 4 + i) * ldh + c0 + tx * 4] = v;
    }
}

// ------- symmetric batched pd, upper-triangle blocks, 128x128 tile 8x8 micro -------
template<int K>
__global__ __launch_bounds__(256) void k_pd_sym(
    const float* __restrict__ X, int ldx,
    const float* __restrict__ xx, float* __restrict__ pd)
{
    __shared__ float As[16][132];
    __shared__ float Bs[16][132];
    int b = blockIdx.y;
    int tid = threadIdx.x;
    int tx = tid & 15, ty = tid >> 4;
    int t = blockIdx.x, rb = 0, rem = 8;
    while (t >= rem) { t -= rem; ++rb; --rem; }
    int cb = rb + t;
    int r0 = rb * 128, c0 = cb * 128;
    const float* Xb = X + (size_t)b * NPTS * ldx;
    int lk = tid & 15, lr = tid >> 4;
    float acc[8][8] = {};
    for (int k0 = 0; k0 < K; k0 += 16) {
#pragma unroll
        for (int i = 0; i < 8; ++i) {
            int row = lr + i * 16;
            int kk = k0 + lk;
            float av = 0.f, bv = 0.f;
            if (kk < K) {
                av = Xb[(size_t)(r0 + row) * ldx + kk];
                bv = Xb[(size_t)(c0 + row) * ldx + kk];
            }
            As[lk][row] = av;
            Bs[lk][row] = bv;
        }
        __syncthreads();
#pragma unroll
        for (int k = 0; k < 16; ++k) {
            float a[8], bb[8];
            *(float4*)&a[0]  = *(const float4*)&As[k][ty * 4];
            *(float4*)&a[4]  = *(const float4*)&As[k][64 + ty * 4];
            *(float4*)&bb[0] = *(const float4*)&Bs[k][tx * 4];
            *(float4*)&bb[4] = *(const float4*)&Bs[k][64 + tx * 4];
#pragma unroll
            for (int i = 0; i < 8; ++i)
#pragma unroll
                for (int j = 0; j < 8; ++j)
                    acc[i][j] = fmaf(a[i], bb[j], acc[i][j]);
        }
        __syncthreads();
    }
    const float* xxb = xx + (size_t)b * NPTS;
    float* pdb = pd + (size_t)b * NPTS * NPTS;
    float xc[8];
#pragma unroll
    for (int j = 0; j < 8; ++j)
        xc[j] = xxb[c0 + ((j < 4) ? (tx * 4 + j) : (64 + tx * 4 + j - 4))];
    float xr[8];
#pragma unroll
    for (int i = 0; i < 8; ++i)
        xr[i] = xxb[r0 + ((i < 4) ? (ty * 4 + i) : (64 + ty * 4 + i - 4))];
#pragma unroll
    for (int i = 0; i < 8; ++i) {
        int r = r0 + ((i < 4) ? (ty * 4 + i) : (64 + ty * 4 + i - 4));
        float* orow = &pdb[(size_t)r * NPTS + c0];
        float4 v0, v1;
        v0.x = 2.f * acc[i][0] - xr[i] - xc[0];
        v0.y = 2.f * acc[i][1] - xr[i] - xc[1];
        v0.z = 2.f * acc[i][2] - xr[i] - xc[2];
        v0.w = 2.f * acc[i][3] - xr[i] - xc[3];
        v1.x = 2.f * acc[i][4] - xr[i] - xc[4];
        v1.y = 2.f * acc[i][5] - xr[i] - xc[5];
        v1.z = 2.f * acc[i][6] - xr[i] - xc[6];
        v1.w = 2.f * acc[i][7] - xr[i] - xc[7];
        *(float4*)&orow[tx * 4]      = v0;
        *(float4*)&orow[64 + tx * 4] = v1;
    }
    if (cb > rb) {
#pragma unroll
        for (int j = 0; j < 8; ++j) {
            int c = c0 + ((j < 4) ? (tx * 4 + j) : (64 + tx * 4 + j - 4));
            float* orow = &pdb[(size_t)c * NPTS + r0];
            float4 w0, w1;
            w0.x = 2.f * acc[0][j] - xc[j] - xr[0];
            w0.y = 2.f * acc[1][j] - xc[j] - xr[1];
            w0.z = 2.f * acc[2][j] - xc[j] - xr[2];
            w0.w = 2.f * acc[3][j] - xc[j] - xr[3];
            w1.x = 2.f * acc[4][j] - xc[j] - xr[4];
            w1.y = 2.f * acc[5][j] - xc[j] - xr[5];
            w1.z = 2.f * acc[6][j] - xc[j] - xr[6];
            w1.w = 2.f * acc[7][j] - xc[j] - xr[7];
            *(float4*)&orow[ty * 4]      = w0;
            *(float4*)&orow[64 + ty * 4] = w1;
        }
    }
}

// ---------------- wave-per-row top-k (k=20), ties -> smaller index ----------------
__global__ __launch_bounds__(256) void k_topk_wave(const float* __restrict__ pd, int* __restrict__ idx) {
    int wid = (blockIdx.x * 256 + threadIdx.x) >> 6;
    int lane = threadIdx.x & 63;
    const float* row = pd + (size_t)wid * NPTS;
    float v[16];
#pragma unroll
    for (int j = 0; j < 16; ++j) v[j] = row[lane + 64 * j];
    float bv = v[0]; int bj = 0;
#pragma unroll
    for (int j = 1; j < 16; ++j) if (v[j] > bv) { bv = v[j]; bj = j; }
    int* out = idx + (size_t)wid * KNN;
    for (int kk = 0; kk < KNN; ++kk) {
        float cv = bv;
        int ci = lane + (bj << 6);
#pragma unroll
        for (int s = 1; s < 64; s <<= 1) {
            float ov = __shfl_xor(cv, s);
            int oi = __shfl_xor(ci, s);
            if (ov > cv || (ov == cv && oi < ci)) { cv = ov; ci = oi; }
        }
        if (lane == 0) out[kk] = ci;
        bool mine = (ci & 63) == lane;
        int jdead = ci >> 6;
#pragma unroll
        for (int j = 0; j < 16; ++j) if (mine && j == jdead) v[j] = -FLT_MAX;
        bv = v[0]; bj = 0;
#pragma unroll
        for (int j = 1; j < 16; ++j) if (v[j] > bv) { bv = v[j]; bj = j; }
    }
}

// ================= split-bf16 helpers =================
__device__ __forceinline__ void split2(float x, ushort& h, ushort& l) {
    uint u = __float_as_uint(x);
    uint r = u + 0x7FFFu + ((u >> 16) & 1u);
    ushort hh = (ushort)(r >> 16);
    float hf = __uint_as_float((uint)hh << 16);
    float d = x - hf;
    uint u2 = __float_as_uint(d);
    uint r2 = u2 + 0x7FFFu + ((u2 >> 16) & 1u);
    h = hh;
    l = (ushort)(r2 >> 16);
}

__device__ __forceinline__ uint pack2(ushort a, ushort b) { return (uint)a | ((uint)b << 16); }

__device__ __forceinline__ void stage_split(const float* __restrict__ g,
                                            ushort* __restrict__ dh, ushort* __restrict__ dl) {
    float4 v0 = *(const float4*)(g);
    float4 v1 = *(const float4*)(g + 4);
    float4 v2 = *(const float4*)(g + 8);
    float4 v3 = *(const float4*)(g + 12);
    float xs[16] = {v0.x, v0.y, v0.z, v0.w, v1.x, v1.y, v1.z, v1.w,
                    v2.x, v2.y, v2.z, v2.w, v3.x, v3.y, v3.z, v3.w};
    ushort h[16], l[16];
#pragma unroll
    for (int i = 0; i < 16; ++i) split2(xs[i], h[i], l[i]);
    uint4 H0, H1, L0, L1;
    H0.x = pack2(h[0], h[1]);  H0.y = pack2(h[2], h[3]);
    H0.z = pack2(h[4], h[5]);  H0.w = pack2(h[6], h[7]);
    H1.x = pack2(h[8], h[9]);  H1.y = pack2(h[10], h[11]);
    H1.z = pack2(h[12], h[13]); H1.w = pack2(h[14], h[15]);
    L0.x = pack2(l[0], l[1]);  L0.y = pack2(l[2], l[3]);
    L0.z = pack2(l[4], l[5]);  L0.w = pack2(l[6], l[7]);
    L1.x = pack2(l[8], l[9]);  L1.y = pack2(l[10], l[11]);
    L1.z = pack2(l[12], l[13]); L1.w = pack2(l[14], l[15]);
    *(uint4*)(dh)     = H0;
    *(uint4*)(dh + 8) = H1;
    *(uint4*)(dl)     = L0;
    *(uint4*)(dl + 8) = L1;
}

// pre-split an fp32 array into hi/lo bf16 arrays (8 elems per thread)
__global__ void k_split(const float* __restrict__ X, ushort* __restrict__ Xh,
                        ushort* __restrict__ Xl, int n) {
    int g = (blockIdx.x * 256 + threadIdx.x) * 8;
    if (g >= n) return;
    float4 a = *(const float4*)(X + g);
    float4 b = *(const float4*)(X + g + 4);
    float xs[8] = {a.x, a.y, a.z, a.w, b.x, b.y, b.z, b.w};
    ushort h[8], l[8];
#pragma unroll
    for (int i = 0; i < 8; ++i) split2(xs[i], h[i], l[i]);
    uint4 H, L;
    H.x = pack2(h[0], h[1]); H.y = pack2(h[2], h[3]);
    H.z = pack2(h[4], h[5]); H.w = pack2(h[6], h[7]);
    L.x = pack2(l[0], l[1]); L.y = pack2(l[2], l[3]);
    L.z = pack2(l[4], l[5]); L.w = pack2(l[6], l[7]);
    *(uint4*)(Xh + g) = H;
    *(uint4*)(Xl + g) = L;
}

// conv5 GEMM shared epilogue macro'd via functions below.
#define LDK 40

__device__ __forceinline__ void gemm5_core(
    int tid, const ushort* sAh, const ushort* sAl, const ushort* sBh, const ushort* sBl,
    f32x4 (&acc)[4][4], int wm, int wn, int fr, int kg)
{
    bf16x8 ah[4], al[4];
#pragma unroll
    for (int mi = 0; mi < 4; ++mi) {
        int rr = wm * 64 + mi * 16 + fr;
        ah[mi] = *(const bf16x8*)&sAh[rr * LDK + kg];
        al[mi] = *(const bf16x8*)&sAl[rr * LDK + kg];
    }
#pragma unroll
    for (int ni = 0; ni < 4; ++ni) {
        int cc = wn * 64 + ni * 16 + fr;
        bf16x8 bh = *(const bf16x8*)&sBh[cc * LDK + kg];
        bf16x8 bl = *(const bf16x8*)&sBl[cc * LDK + kg];
#pragma unroll
        for (int mi = 0; mi < 4; ++mi) {
            acc[mi][ni] = __builtin_amdgcn_mfma_f32_16x16x32_bf16(ah[mi], bh, acc[mi][ni], 0, 0, 0);
            acc[mi][ni] = __builtin_amdgcn_mfma_f32_16x16x32_bf16(ah[mi], bl, acc[mi][ni], 0, 0, 0);
            acc[mi][ni] = __builtin_amdgcn_mfma_f32_16x16x32_bf16(al[mi], bh, acc[mi][ni], 0, 0, 0);
        }
    }
}

__device__ __forceinline__ void gemm5_epilogue(
    int tid, int lane, int wm, int wn, int fr, int r0, int c0,
    f32x4 (&acc)[4][4], float* H, float* sums, ushort* scratch)
{
#pragma unroll
    for (int mi = 0; mi < 4; ++mi) {
        int rg = r0 + wm * 64 + mi * 16 + (lane >> 4) * 4;
#pragma unroll
        for (int ni = 0; ni < 4; ++ni) {
            int cg = c0 + wn * 64 + ni * 16 + fr;
#pragma unroll
            for (int r = 0; r < 4; ++r)
                H[(size_t)(rg + r) * 1024 + cg] = acc[mi][ni][r];
        }
    }
    float* csum  = (float*)scratch;
    float* csum2 = csum + 128;
    if (tid < 128) { csum[tid] = 0.f; csum2[tid] = 0.f; }
    __syncthreads();
#pragma unroll
    for (int ni = 0; ni < 4; ++ni) {
        float s = 0.f, s2 = 0.f;
#pragma unroll
        for (int mi = 0; mi < 4; ++mi)
#pragma unroll
            for (int r = 0; r < 4; ++r) { float v = acc[mi][ni][r]; s += v; s2 += v * v; }
        int c = wn * 64 + ni * 16 + fr;
        atomicAdd(&csum[c], s);
        atomicAdd(&csum2[c], s2);
    }
    __syncthreads();
    if (tid < 128) {
        atomicAdd(&sums[c0 + tid], csum[tid]);
        atomicAdd(&sums[1024 + c0 + tid], csum2[tid]);
    }
}

// variant 1: in-kernel A split (fallback when ws is tight)
__global__ __launch_bounds__(256) void k_gemm5_mfma(
    const float* __restrict__ X, const ushort* __restrict__ Wh, const ushort* __restrict__ Wl,
    float* __restrict__ H, float* __restrict__ sums)
{
    __shared__ __align__(16) ushort sAh[128 * LDK];
    __shared__ __align__(16) ushort sAl[128 * LDK];
    __shared__ __align__(16) ushort sBh[128 * LDK];
    __shared__ __align__(16) ushort sBl[128 * LDK];
    int tid = threadIdx.x;
    int lane = tid & 63, w = tid >> 6;
    int wm = w >> 1, wn = w & 1;
    int bid = blockIdx.x;
    int wg = (bid & 7) * 256 + (bid >> 3);
    int cb = wg & 7, rb = wg >> 3;
    int r0 = rb * 128, c0 = cb * 128;
    int srow = tid >> 1, sk = (tid & 1) * 16;
    int fr = lane & 15;
    int kg = (lane >> 4) << 3;
    f32x4 acc[4][4] = {};
    for (int k0 = 0; k0 < 640; k0 += 32) {
        stage_split(X + (size_t)(r0 + srow) * 640 + k0 + sk,
                    &sAh[srow * LDK + sk], &sAl[srow * LDK + sk]);
        {
            size_t gb = (size_t)(c0 + srow) * 640 + k0 + sk;
            *(uint4*)&sBh[srow * LDK + sk]     = *(const uint4*)(Wh + gb);
            *(uint4*)&sBh[srow * LDK + sk + 8] = *(const uint4*)(Wh + gb + 8);
            *(uint4*)&sBl[srow * LDK + sk]     = *(const uint4*)(Wl + gb);
            *(uint4*)&sBl[srow * LDK + sk + 8] = *(const uint4*)(Wl + gb + 8);
        }
        __syncthreads();
        gemm5_core(tid, sAh, sAl, sBh, sBl, acc, wm, wn, fr, kg);
        __syncthreads();
    }
    gemm5_epilogue(tid, lane, wm, wn, fr, r0, c0, acc, H, sums, sAh);
}

// variant 2: pre-split A (bit-identical inputs, pure copy staging)
__global__ __launch_bounds__(256) void k_gemm5_pre(
    const ushort* __restrict__ Ah, const ushort* __restrict__ Al,
    const ushort* __restrict__ Wh, const ushort* __restrict__ Wl,
    float* __restrict__ H, float* __restrict__ sums)
{
    __shared__ __align__(16) ushort sAh[128 * LDK];
    __shared__ __align__(16) ushort sAl[128 * LDK];
    __shared__ __align__(16) ushort sBh[128 * LDK];
    __shared__ __align__(16) ushort sBl[128 * LDK];
    int tid = threadIdx.x;
    int lane = tid & 63, w = tid >> 6;
    int wm = w >> 1, wn = w & 1;
    int bid = blockIdx.x;
    int wg = (bid & 7) * 256 + (bid >> 3);
    int cb = wg & 7, rb = wg >> 3;
    int r0 = rb * 128, c0 = cb * 128;
    int srow = tid >> 1, sk = (tid & 1) * 16;
    int fr = lane & 15;
    int kg = (lane >> 4) << 3;
    f32x4 acc[4][4] = {};
    for (int k0 = 0; k0 < 640; k0 += 32) {
        size_t ga = (size_t)(r0 + srow) * 640 + k0 + sk;
        *(uint4*)&sAh[srow * LDK + sk]     = *(const uint4*)(Ah + ga);
        *(uint4*)&sAh[srow * LDK + sk + 8] = *(const uint4*)(Ah + ga + 8);
        *(uint4*)&sAl[srow * LDK + sk]     = *(const uint4*)(Al + ga);
        *(uint4*)&sAl[srow * LDK + sk + 8] = *(const uint4*)(Al + ga + 8);
        size_t gb = (size_t)(c0 + srow) * 640 + k0 + sk;
        *(uint4*)&sBh[srow * LDK + sk]     = *(const uint4*)(Wh + gb);
        *(uint4*)&sBh[srow * LDK + sk + 8] = *(const uint4*)(Wh + gb + 8);
        *(uint4*)&sBl[srow * LDK + sk]     = *(const uint4*)(Wl + gb);
        *(uint4*)&sBl[srow * LDK + sk + 8] = *(const uint4*)(Wl + gb + 8);
        __syncthreads();
        gemm5_core(tid, sAh, sAl, sBh, sBl, acc, wm, wn, fr, kg);
        __syncthreads();
    }
    gemm5_epilogue(tid, lane, wm, wn, fr, r0, c0, acc, H, sums, sAh);
}

// ---------------- BN stats ----------------
__global__ __launch_bounds__(256) void k_bn_stats(const float* __restrict__ H, int ldh, int O, int R,
                                                  float* __restrict__ sums) {
    int nblk = gridDim.x;
    int rows = (R + nblk - 1) / nblk;
    int r0 = blockIdx.x * rows;
    int r1 = r0 + rows; if (r1 > R) r1 = R;
    int tid = threadIdx.x;
    if (O <= 256) {
        int per = 256 / O;
        int c = tid % O;
        int rOff = tid / O;
        float s = 0.f, s2 = 0.f;
        for (int r = r0 + rOff; r < r1; r += per) {
            float v = H[(size_t)r * ldh + c];
            s += v; s2 += v * v;
        }
        __shared__ float ls[256], ls2[256];
        ls[tid] = s; ls2[tid] = s2;
        __syncthreads();
        for (int st = 128; st >= O; st >>= 1) {
            if (tid < st) { ls[tid] += ls[tid + st]; ls2[tid] += ls2[tid + st]; }
            __syncthreads();
        }
        if (tid < O) {
            atomicAdd(&sums[c], ls[tid]);
            atomicAdd(&sums[O + c], ls2[tid]);
        }
    } else {
        int nc = O / 256;
        float s[4] = {0, 0, 0, 0}, s2[4] = {0, 0, 0, 0};
        for (int r = r0; r < r1; ++r) {
            const float* rowp = H + (size_t)r * ldh;
            for (int i = 0; i < nc; ++i) {
                float v = rowp[tid + i * 256];
                s[i] += v; s2[i] += v * v;
            }
        }
        for (int i = 0; i < nc; ++i) {
            atomicAdd(&sums[tid + i * 256], s[i]);
            atomicAdd(&sums[O + tid + i * 256], s2[i]);
        }
    }
}

// ---------------- BN finalize ----------------
__global__ void k_bn_finalize(const float* __restrict__ sums, const float* __restrict__ g,
                              const float* __restrict__ bta, int O, float invR,
                              float* __restrict__ ss) {
    int o = blockIdx.x * 256 + threadIdx.x;
    if (o >= O) return;
    float mu = sums[o] * invR;
    float var = sums[O + o] * invR - mu * mu;
    float sc = g[o] / sqrtf(var + 1e-5f);
    ss[o] = sc;
    ss[O + o] = bta[o] - mu * sc;
}

// ---------------- graph_feature (+ optional split-bf16 dual write) ----------------
__global__ __launch_bounds__(256) void k_graph_feature(
    const float* __restrict__ hT, int ldh, int C,
    const int* __restrict__ idx, const float* __restrict__ ss,
    float* __restrict__ out, int ldo, int colOff,
    ushort* __restrict__ outh, ushort* __restrict__ outl)
{
    int ppb = 256 / C;
    int p = threadIdx.x / C;
    int c = threadIdx.x % C;
    int r = blockIdx.x * ppb + p;
    int b = r >> 10;
    float sc = ss[c], sh = ss[C + c];
    float self = hT[(size_t)r * ldh + c];
    float vs = lrelu(sc * self + sh);
    const int* ip = idx + (size_t)r * KNN;
    float m = -FLT_MAX;
#pragma unroll 4
    for (int k = 0; k < KNN; ++k) {
        int j = ip[k];
        float hv = hT[((size_t)b * NPTS + j) * ldh + c];
        float v = lrelu(sc * hv + sh);
        m = fmaxf(m, v);
    }
    float diff = m - vs;
    size_t base = (size_t)r * ldo + colOff;
    out[base + c] = vs;
    out[base + C + c] = diff;
    if (outh) {
        ushort hh, ll;
        split2(vs, hh, ll);
        outh[base + c] = hh; outl[base + c] = ll;
        split2(diff, hh, ll);
        outh[base + C + c] = hh; outl[base + C + c] = ll;
    }
}

// ---------------- channel max for conv5 ----------------
__global__ __launch_bounds__(256) void k_chanmax(const float* __restrict__ h5,
                                                 const float* __restrict__ ss,
                                                 float* __restrict__ feat) {
    int r = blockIdx.x;
    int tid = threadIdx.x;
    __shared__ float red[256];
    const float* rowp = h5 + (size_t)r * 1024;
    float m = -FLT_MAX;
    for (int o = tid; o < 1024; o += 256) {
        float v = lrelu(ss[o] * rowp[o] + ss[1024 + o]);
        m = fmaxf(m, v);
    }
    red[tid] = m;
    __syncthreads();
    for (int s = 128; s > 0; s >>= 1) {
        if (tid < s) red[tid] = fmaxf(red[tid], red[tid + s]);
        __syncthreads();
    }
    if (tid == 0) feat[r] = red[0];
}

// ---------------- FC ----------------
__global__ void k_fc(const float* __restrict__ in, const float* __restrict__ Lw,
                     const float* __restrict__ bias, float* __restrict__ out, int K, int J) {
    int g = blockIdx.x * 256 + threadIdx.x;
    if (g >= 32 * J) return;
    int b = g / J, j = g % J;
    const float* xr = in + (size_t)b * K;
    const float* wr = Lw + (size_t)j * K;
    float acc = 0.f;
    for (int k = 0; k < K; ++k) acc = fmaf(xr[k], wr[k], acc);
    out[g] = bias ? acc + bias[j] : acc;
}

// ---------------- BN1d over batch (32) + lrelu, in place ----------------
__global__ void k_bn1d(float* __restrict__ h, const float* __restrict__ g,
                       const float* __restrict__ bta, int J) {
    int j = blockIdx.x * 256 + threadIdx.x;
    if (j >= J) return;
    float s = 0.f, s2 = 0.f;
    for (int b = 0; b < 32; ++b) {
        float v = h[b * J + j];
        s += v; s2 += v * v;
    }
    float mu = s / 32.f;
    float var = s2 / 32.f - mu * mu;
    float sc = g[j] / sqrtf(var + 1e-5f);
    float sh = bta[j] - mu * sc;
    for (int b = 0; b < 32; ++b) {
        float v = sc * h[b * J + j] + sh;
        h[b * J + j] = lrelu(v);
    }
}

extern "C" void kernel_launch(void* const* d_in, const int* in_sizes, int n_in,
                              void* d_out, int out_size, void* d_ws, size_t ws_size,
                              hipStream_t stream) {
    const float* x   = (const float*)d_in[0];
    const float* W1  = (const float*)d_in[1];
    const float* g1  = (const float*)d_in[2];
    const float* b1  = (const float*)d_in[3];
    const float* W2  = (const float*)d_in[4];
    const float* g2  = (const float*)d_in[5];
    const float* b2  = (const float*)d_in[6];
    const float* W3  = (const float*)d_in[7];
    const float* g3  = (const float*)d_in[8];
    const float* b3  = (const float*)d_in[9];
    const float* W4  = (const float*)d_in[10];
    const float* g4  = (const float*)d_in[11];
    const float* b4  = (const float*)d_in[12];
    const float* W5  = (const float*)d_in[13];
    const float* g5  = (const float*)d_in[14];
    const float* b5  = (const float*)d_in[15];
    const float* L1  = (const float*)d_in[16];
    const float* g6  = (const float*)d_in[17];
    const float* b6  = (const float*)d_in[18];
    const float* L2  = (const float*)d_in[19];
    const float* bl2 = (const float*)d_in[20];
    const float* g7  = (const float*)d_in[21];
    const float* b7  = (const float*)d_in[22];
    const float* L3  = (const float*)d_in[23];
    const float* bl3 = (const float*)d_in[24];

    float* ws = (float*)d_ws;
    size_t off = 0;
    auto alloc = [&](size_t n) { size_t o = off; off += (n + 63) & ~(size_t)63; return o; };
    float* pd   = ws + alloc((size_t)NB * NPTS * NPTS);  // 134 MB, aliased with h5
    float* h5   = pd;
    float* xcT  = ws + alloc((size_t)RTOT * 640);
    float* hbuf = ws + alloc((size_t)RTOT * 128);
    float* xT   = ws + alloc((size_t)RTOT * 3);
    float* xxb  = ws + alloc(RTOT);
    float* sumsA = ws + alloc(2048 * 5);   // arena: conv1..4 + gemm5 stats, zeroed once
    float* ss   = ws + alloc(2048);
    float* feat = ws + alloc(RTOT);
    float* h1   = ws + alloc(32 * 512);
    float* h2   = ws + alloc(32 * 256);
    int*   idxb = (int*)(ws + alloc((size_t)RTOT * KNN));
    ushort* W5h = (ushort*)(ws + alloc(1024 * 640 / 2));
    ushort* W5l = (ushort*)(ws + alloc(1024 * 640 / 2));
    size_t base_floats = off;
    // optional pre-split A arrays (84 MB) — only if workspace allows
    size_t presplit_floats = base_floats + 2 * ((size_t)RTOT * 320 + 64);
    bool use_pre = (presplit_floats * sizeof(float) <= ws_size);
    ushort* xcTh = nullptr; ushort* xcTl = nullptr;
    if (use_pre) {
        xcTh = (ushort*)(ws + alloc((size_t)RTOT * 320));
        xcTl = (ushort*)(ws + alloc((size_t)RTOT * 320));
    }

    k_transpose_x<<<(NB * 3 * NPTS + 255) / 256, 256, 0, stream>>>(x, xT);
    k_split<<<(1024 * 640 / 8 + 255) / 256, 256, 0, stream>>>(W5, W5h, W5l, 1024 * 640);
    hipMemsetAsync(sumsA, 0, 2048 * 5 * sizeof(float), stream);

    auto run_knn = [&](const float* X, int ldx, int C) {
        k_xx<<<(RTOT + 255) / 256, 256, 0, stream>>>(X, ldx, C, xxb);
        if (C == 3)
            k_pd_sym<3><<<dim3(36, NB), 256, 0, stream>>>(X, ldx, xxb, pd);
        else
            k_pd_sym<128><<<dim3(36, NB), 256, 0, stream>>>(X, ldx, xxb, pd);
        k_topk_wave<<<RTOT / 4, 256, 0, stream>>>(pd, idxb);
    };
    auto run_conv = [&](const float* X, int ldx, int K, const float* W,
                        const float* g, const float* bta, int O, float* sums) {
        k_gemm_xwt<<<dim3(O / 64, RTOT / 64), 256, 0, stream>>>(X, ldx, K, W, hbuf, O);
        k_bn_stats<<<256, 256, 0, stream>>>(hbuf, O, O, RTOT, sums);
        k_bn_finalize<<<(O + 255) / 256, 256, 0, stream>>>(sums, g, bta, O, 1.f / RTOT, ss);
    };
    auto run_gf = [&](int C, int colOff) {
        int ppb = 256 / C;
        k_graph_feature<<<RTOT / ppb, 256, 0, stream>>>(hbuf, C, C, idxb, ss, xcT, 640, colOff,
                                                        xcTh, xcTl);
    };

    // stage 1
    run_knn(xT, 3, 3);
    run_conv(xT, 3, 3, W1, g1, b1, 64, sumsA);
    run_gf(64, 0);

    // stage 2
    run_knn(xcT + 0, 640, 128);
    run_conv(xcT + 0, 640, 128, W2, g2, b2, 64, sumsA + 2048);
    run_gf(64, 128);

    // stage 3
    run_knn(xcT + 128, 640, 128);
    run_conv(xcT + 128, 640, 128, W3, g3, b3, 64, sumsA + 4096);
    run_gf(64, 256);

    // stage 4
    run_knn(xcT + 256, 640, 128);
    run_conv(xcT + 256, 640, 128, W4, g4, b4, 128, sumsA + 6144);
    run_gf(128, 384);

    // conv5 (BN fused into epilogue) + chan-max
    float* sums5 = sumsA + 8192;
    if (use_pre)
        k_gemm5_pre<<<2048, 256, 0, stream>>>(xcTh, xcTl, W5h, W5l, h5, sums5);
    else
        k_gemm5_mfma<<<2048, 256, 0, stream>>>(xcT, W5h, W5l, h5, sums5);
    k_bn_finalize<<<4, 256, 0, stream>>>(sums5, g5, b5, 1024, 1.f / RTOT, ss);
    k_chanmax<<<RTOT, 256, 0, stream>>>(h5, ss, feat);

    // FC head
    k_fc<<<(32 * 512 + 255) / 256, 256, 0, stream>>>(feat, L1, nullptr, h1, 1024, 512);
    k_bn1d<<<(512 + 255) / 256, 256, 0, stream>>>(h1, g6, b6, 512);
    k_fc<<<(32 * 256 + 255) / 256, 256, 0, stream>>>(h1, L2, bl2, h2, 512, 256);
    k_bn1d<<<(256 + 255) / 256, 256, 0, stream>>>(h2, g7, b7, 256);
    k_fc<<<(32 * 40 + 255) / 256, 256, 0, stream>>>(h2, L3, bl3, (float*)d_out, 256, 40);
}

// Round 9
// 1661.500 us; speedup vs baseline: 1.0590x; 1.0590x over previous
//
#include <hip/hip_runtime.h>
#include <cfloat>
#include <cstdint>

#define NB 32
#define NPTS 1024
#define KNN 20
#define RTOT (NB * NPTS)

typedef __attribute__((ext_vector_type(8))) short bf16x8;
typedef __attribute__((ext_vector_type(4))) float f32x4;

__device__ __forceinline__ float lrelu(float v) { return v >= 0.f ? v : 0.2f * v; }

// ---------------- transpose x (B,3,N) -> xT (B*N, 3) ----------------
__global__ void k_transpose_x(const float* __restrict__ x, float* __restrict__ xT) {
    int g = blockIdx.x * 256 + threadIdx.x;
    if (g >= NB * 3 * NPTS) return;
    int n = g % NPTS;
    int c = (g / NPTS) % 3;
    int b = g / (3 * NPTS);
    xT[((size_t)b * NPTS + n) * 3 + c] = x[g];
}

// ---------------- xx[r] = sum_c X[r,c]^2 ----------------
__global__ void k_xx(const float* __restrict__ X, int ldx, int C, float* __restrict__ xx) {
    int r = blockIdx.x * 256 + threadIdx.x;
    if (r >= RTOT) return;
    const float* p = X + (size_t)r * ldx;
    float s = 0.f;
    for (int c = 0; c < C; ++c) { float v = p[c]; s += v * v; }
    xx[r] = s;
}

// ---------------- 64x64 GEMM (small convs): H[r,o] = sum_k X[r,k]*W[o,k] ----------------
__global__ __launch_bounds__(256) void k_gemm_xwt(
    const float* __restrict__ X, int ldx, int K,
    const float* __restrict__ W,
    float* __restrict__ H, int ldh)
{
    __shared__ float As[16][68];
    __shared__ float Bs[16][68];
    int tid = threadIdx.x;
    int tx = tid & 15, ty = tid >> 4;
    int c0 = blockIdx.x * 64;
    int r0 = blockIdx.y * 64;
    float acc[4][4] = {};
    int lr = tid >> 4, lk = tid & 15;
    for (int k0 = 0; k0 < K; k0 += 16) {
#pragma unroll
        for (int i = 0; i < 4; ++i) {
            int row = lr + i * 16;
            int kk = k0 + lk;
            float av = 0.f, bv = 0.f;
            if (kk < K) {
                av = X[(size_t)(r0 + row) * ldx + kk];
                bv = W[(size_t)(c0 + row) * K + kk];
            }
            As[lk][row] = av;
            Bs[lk][row] = bv;
        }
        __syncthreads();
#pragma unroll
        for (int k = 0; k < 16; ++k) {
            float4 a4 = *(const float4*)&As[k][ty * 4];
            float4 b4 = *(const float4*)&Bs[k][tx * 4];
            float av[4] = {a4.x, a4.y, a4.z, a4.w};
            float bv[4] = {b4.x, b4.y, b4.z, b4.w};
#pragma unroll
            for (int i = 0; i < 4; ++i)
#pragma unroll
                for (int j = 0; j < 4; ++j)
                    acc[i][j] = fmaf(av[i], bv[j], acc[i][j]);
        }
        __syncthreads();
    }
#pragma unroll
    for (int i = 0; i < 4; ++i) {
        float4 v = make_float4(acc[i][0], acc[i][1], acc[i][2], acc[i][3]);
        *(float4*)&H[(size_t)(r0 + ty * 4 + i) * ldh + c0 + tx * 4] = v;
    }
}

// ------- symmetric batched pd, upper-triangle blocks, 128x128 tile 8x8 micro -------
template<int K>
__global__ __launch_bounds__(256) void k_pd_sym(
    const float* __restrict__ X, int ldx,
    const float* __restrict__ xx, float* __restrict__ pd)
{
    __shared__ float As[16][132];
    __shared__ float Bs[16][132];
    int b = blockIdx.y;
    int tid = threadIdx.x;
    int tx = tid & 15, ty = tid >> 4;
    int t = blockIdx.x, rb = 0, rem = 8;
    while (t >= rem) { t -= rem; ++rb; --rem; }
    int cb = rb + t;
    int r0 = rb * 128, c0 = cb * 128;
    const float* Xb = X + (size_t)b * NPTS * ldx;
    int lk = tid & 15, lr = tid >> 4;
    float acc[8][8] = {};
    for (int k0 = 0; k0 < K; k0 += 16) {
#pragma unroll
        for (int i = 0; i < 8; ++i) {
            int row = lr + i * 16;
            int kk = k0 + lk;
            float av = 0.f, bv = 0.f;
            if (kk < K) {
                av = Xb[(size_t)(r0 + row) * ldx + kk];
                bv = Xb[(size_t)(c0 + row) * ldx + kk];
            }
            As[lk][row] = av;
            Bs[lk][row] = bv;
        }
        __syncthreads();
#pragma unroll
        for (int k = 0; k < 16; ++k) {
            float a[8], bb[8];
            *(float4*)&a[0]  = *(const float4*)&As[k][ty * 4];
            *(float4*)&a[4]  = *(const float4*)&As[k][64 + ty * 4];
            *(float4*)&bb[0] = *(const float4*)&Bs[k][tx * 4];
            *(float4*)&bb[4] = *(const float4*)&Bs[k][64 + tx * 4];
#pragma unroll
            for (int i = 0; i < 8; ++i)
#pragma unroll
                for (int j = 0; j < 8; ++j)
                    acc[i][j] = fmaf(a[i], bb[j], acc[i][j]);
        }
        __syncthreads();
    }
    const float* xxb = xx + (size_t)b * NPTS;
    float* pdb = pd + (size_t)b * NPTS * NPTS;
    float xc[8];
#pragma unroll
    for (int j = 0; j < 8; ++j)
        xc[j] = xxb[c0 + ((j < 4) ? (tx * 4 + j) : (64 + tx * 4 + j - 4))];
    float xr[8];
#pragma unroll
    for (int i = 0; i < 8; ++i)
        xr[i] = xxb[r0 + ((i < 4) ? (ty * 4 + i) : (64 + ty * 4 + i - 4))];
#pragma unroll
    for (int i = 0; i < 8; ++i) {
        int r = r0 + ((i < 4) ? (ty * 4 + i) : (64 + ty * 4 + i - 4));
        float* orow = &pdb[(size_t)r * NPTS + c0];
        float4 v0, v1;
        v0.x = 2.f * acc[i][0] - xr[i] - xc[0];
        v0.y = 2.f * acc[i][1] - xr[i] - xc[1];
        v0.z = 2.f * acc[i][2] - xr[i] - xc[2];
        v0.w = 2.f * acc[i][3] - xr[i] - xc[3];
        v1.x = 2.f * acc[i][4] - xr[i] - xc[4];
        v1.y = 2.f * acc[i][5] - xr[i] - xc[5];
        v1.z = 2.f * acc[i][6] - xr[i] - xc[6];
        v1.w = 2.f * acc[i][7] - xr[i] - xc[7];
        *(float4*)&orow[tx * 4]      = v0;
        *(float4*)&orow[64 + tx * 4] = v1;
    }
    if (cb > rb) {
#pragma unroll
        for (int j = 0; j < 8; ++j) {
            int c = c0 + ((j < 4) ? (tx * 4 + j) : (64 + tx * 4 + j - 4));
            float* orow = &pdb[(size_t)c * NPTS + r0];
            float4 w0, w1;
            w0.x = 2.f * acc[0][j] - xc[j] - xr[0];
            w0.y = 2.f * acc[1][j] - xc[j] - xr[1];
            w0.z = 2.f * acc[2][j] - xc[j] - xr[2];
            w0.w = 2.f * acc[3][j] - xc[j] - xr[3];
            w1.x = 2.f * acc[4][j] - xc[j] - xr[4];
            w1.y = 2.f * acc[5][j] - xc[j] - xr[5];
            w1.z = 2.f * acc[6][j] - xc[j] - xr[6];
            w1.w = 2.f * acc[7][j] - xc[j] - xr[7];
            *(float4*)&orow[ty * 4]      = w0;
            *(float4*)&orow[64 + ty * 4] = w1;
        }
    }
}

// ---------------- wave-per-row top-k (k=20), ties -> smaller index ----------------
__global__ __launch_bounds__(256) void k_topk_wave(const float* __restrict__ pd, int* __restrict__ idx) {
    int wid = (blockIdx.x * 256 + threadIdx.x) >> 6;
    int lane = threadIdx.x & 63;
    const float* row = pd + (size_t)wid * NPTS;
    float v[16];
#pragma unroll
    for (int j = 0; j < 16; ++j) v[j] = row[lane + 64 * j];
    float bv = v[0]; int bj = 0;
#pragma unroll
    for (int j = 1; j < 16; ++j) if (v[j] > bv) { bv = v[j]; bj = j; }
    int* out = idx + (size_t)wid * KNN;
    for (int kk = 0; kk < KNN; ++kk) {
        float cv = bv;
        int ci = lane + (bj << 6);
#pragma unroll
        for (int s = 1; s < 64; s <<= 1) {
            float ov = __shfl_xor(cv, s);
            int oi = __shfl_xor(ci, s);
            if (ov > cv || (ov == cv && oi < ci)) { cv = ov; ci = oi; }
        }
        if (lane == 0) out[kk] = ci;
        bool mine = (ci & 63) == lane;
        int jdead = ci >> 6;
#pragma unroll
        for (int j = 0; j < 16; ++j) if (mine && j == jdead) v[j] = -FLT_MAX;
        bv = v[0]; bj = 0;
#pragma unroll
        for (int j = 1; j < 16; ++j) if (v[j] > bv) { bv = v[j]; bj = j; }
    }
}

// ================= split-bf16 helpers =================
__device__ __forceinline__ void split2(float x, ushort& h, ushort& l) {
    uint u = __float_as_uint(x);
    uint r = u + 0x7FFFu + ((u >> 16) & 1u);
    ushort hh = (ushort)(r >> 16);
    float hf = __uint_as_float((uint)hh << 16);
    float d = x - hf;
    uint u2 = __float_as_uint(d);
    uint r2 = u2 + 0x7FFFu + ((u2 >> 16) & 1u);
    h = hh;
    l = (ushort)(r2 >> 16);
}

__device__ __forceinline__ uint pack2(ushort a, ushort b) { return (uint)a | ((uint)b << 16); }

// read 8 consecutive f32; write 8 hi-bf16 + 8 lo-bf16 (16B-aligned dests)
__device__ __forceinline__ void stage_split8(const float* __restrict__ g,
                                             ushort* __restrict__ dh, ushort* __restrict__ dl) {
    float4 a = *(const float4*)(g);
    float4 b = *(const float4*)(g + 4);
    float xs[8] = {a.x, a.y, a.z, a.w, b.x, b.y, b.z, b.w};
    ushort h[8], l[8];
#pragma unroll
    for (int i = 0; i < 8; ++i) split2(xs[i], h[i], l[i]);
    uint4 H, L;
    H.x = pack2(h[0], h[1]); H.y = pack2(h[2], h[3]);
    H.z = pack2(h[4], h[5]); H.w = pack2(h[6], h[7]);
    L.x = pack2(l[0], l[1]); L.y = pack2(l[2], l[3]);
    L.z = pack2(l[4], l[5]); L.w = pack2(l[6], l[7]);
    *(uint4*)(dh) = H;
    *(uint4*)(dl) = L;
}

// pre-split an fp32 array into hi/lo bf16 arrays (8 elems per thread)
__global__ void k_split(const float* __restrict__ X, ushort* __restrict__ Xh,
                        ushort* __restrict__ Xl, int n) {
    int g = (blockIdx.x * 256 + threadIdx.x) * 8;
    if (g >= n) return;
    stage_split8(X + g, Xh + g, Xl + g);
}

// conv5 GEMM: H[r,o] = sum_k X[r,k]*W[o,k]; X (32768x640 f32), W pre-split bf16.
// 128x256 block tile, 512 threads = 8 waves (2x4) of 64x64, mfma_f32_16x16x32_bf16,
// 3-pass hi/lo (hh, hl, lh — ascending k; bit-identical to the 128x128 version).
// XCD-chunked grid: each row-panel's 4 col-blocks run consecutively on one XCD.
// BN column stats fused into epilogue (sums zeroed before launch).
#define LDK 40
__global__ __launch_bounds__(512) void k_gemm5_mfma(
    const float* __restrict__ X, const ushort* __restrict__ Wh, const ushort* __restrict__ Wl,
    float* __restrict__ H, float* __restrict__ sums)
{
    __shared__ __align__(16) ushort sAh[128 * LDK];
    __shared__ __align__(16) ushort sAl[128 * LDK];
    __shared__ __align__(16) ushort sBh[256 * LDK];
    __shared__ __align__(16) ushort sBl[256 * LDK];
    int tid = threadIdx.x;
    int lane = tid & 63, w = tid >> 6;       // 8 waves
    int wm = w >> 2, wn = w & 3;             // 2 x 4 wave grid of 64x64 tiles
    int bid = blockIdx.x;
    int wg = (bid & 7) * 128 + (bid >> 3);   // XCD-chunked remap (1024 % 8 == 0)
    int cb = wg & 3, rb = wg >> 2;           // 4 col-blocks x 256 row-blocks
    int r0 = rb * 128, c0 = cb * 256;
    int srA = tid >> 2, skA = (tid & 3) * 8;   // A: 128 rows x 32 k, 8 elems/thread
    int srB = tid >> 1, skB = (tid & 1) * 16;  // B: 256 rows x 32 k, 16 elems/thread
    int fr = lane & 15;
    int kg = (lane >> 4) << 3;
    f32x4 acc[4][4] = {};
    for (int k0 = 0; k0 < 640; k0 += 32) {
        stage_split8(X + (size_t)(r0 + srA) * 640 + k0 + skA,
                     &sAh[srA * LDK + skA], &sAl[srA * LDK + skA]);
        {
            size_t gb = (size_t)(c0 + srB) * 640 + k0 + skB;
            *(uint4*)&sBh[srB * LDK + skB]     = *(const uint4*)(Wh + gb);
            *(uint4*)&sBh[srB * LDK + skB + 8] = *(const uint4*)(Wh + gb + 8);
            *(uint4*)&sBl[srB * LDK + skB]     = *(const uint4*)(Wl + gb);
            *(uint4*)&sBl[srB * LDK + skB + 8] = *(const uint4*)(Wl + gb + 8);
        }
        __syncthreads();
        bf16x8 ah[4], al[4];
#pragma unroll
        for (int mi = 0; mi < 4; ++mi) {
            int rr = wm * 64 + mi * 16 + fr;
            ah[mi] = *(const bf16x8*)&sAh[rr * LDK + kg];
            al[mi] = *(const bf16x8*)&sAl[rr * LDK + kg];
        }
#pragma unroll
        for (int ni = 0; ni < 4; ++ni) {
            int cc = wn * 64 + ni * 16 + fr;
            bf16x8 bh = *(const bf16x8*)&sBh[cc * LDK + kg];
            bf16x8 bl = *(const bf16x8*)&sBl[cc * LDK + kg];
#pragma unroll
            for (int mi = 0; mi < 4; ++mi) {
                acc[mi][ni] = __builtin_amdgcn_mfma_f32_16x16x32_bf16(ah[mi], bh, acc[mi][ni], 0, 0, 0);
                acc[mi][ni] = __builtin_amdgcn_mfma_f32_16x16x32_bf16(ah[mi], bl, acc[mi][ni], 0, 0, 0);
                acc[mi][ni] = __builtin_amdgcn_mfma_f32_16x16x32_bf16(al[mi], bh, acc[mi][ni], 0, 0, 0);
            }
        }
        __syncthreads();
    }
    // C/D layout: col = lane&15, row = (lane>>4)*4 + reg   [measured m89/m91]
#pragma unroll
    for (int mi = 0; mi < 4; ++mi) {
        int rg = r0 + wm * 64 + mi * 16 + (lane >> 4) * 4;
#pragma unroll
        for (int ni = 0; ni < 4; ++ni) {
            int cg = c0 + wn * 64 + ni * 16 + fr;
#pragma unroll
            for (int r = 0; r < 4; ++r)
                H[(size_t)(rg + r) * 1024 + cg] = acc[mi][ni][r];
        }
    }
    // fused BN stats: per-column sum/sumsq of this block's 128x256 tile (LDS aliased onto dead sAh)
    float* csum  = (float*)sAh;
    float* csum2 = csum + 256;
    if (tid < 256) { csum[tid] = 0.f; csum2[tid] = 0.f; }
    __syncthreads();
#pragma unroll
    for (int ni = 0; ni < 4; ++ni) {
        float s = 0.f, s2 = 0.f;
#pragma unroll
        for (int mi = 0; mi < 4; ++mi)
#pragma unroll
            for (int r = 0; r < 4; ++r) { float v = acc[mi][ni][r]; s += v; s2 += v * v; }
        int c = wn * 64 + ni * 16 + fr;
        atomicAdd(&csum[c], s);
        atomicAdd(&csum2[c], s2);
    }
    __syncthreads();
    if (tid < 256) {
        atomicAdd(&sums[c0 + tid], csum[tid]);
        atomicAdd(&sums[1024 + c0 + tid], csum2[tid]);
    }
}

// ---------------- BN stats ----------------
__global__ __launch_bounds__(256) void k_bn_stats(const float* __restrict__ H, int ldh, int O, int R,
                                                  float* __restrict__ sums) {
    int nblk = gridDim.x;
    int rows = (R + nblk - 1) / nblk;
    int r0 = blockIdx.x * rows;
    int r1 = r0 + rows; if (r1 > R) r1 = R;
    int tid = threadIdx.x;
    if (O <= 256) {
        int per = 256 / O;
        int c = tid % O;
        int rOff = tid / O;
        float s = 0.f, s2 = 0.f;
        for (int r = r0 + rOff; r < r1; r += per) {
            float v = H[(size_t)r * ldh + c];
            s += v; s2 += v * v;
        }
        __shared__ float ls[256], ls2[256];
        ls[tid] = s; ls2[tid] = s2;
        __syncthreads();
        for (int st = 128; st >= O; st >>= 1) {
            if (tid < st) { ls[tid] += ls[tid + st]; ls2[tid] += ls2[tid + st]; }
            __syncthreads();
        }
        if (tid < O) {
            atomicAdd(&sums[c], ls[tid]);
            atomicAdd(&sums[O + c], ls2[tid]);
        }
    } else {
        int nc = O / 256;
        float s[4] = {0, 0, 0, 0}, s2[4] = {0, 0, 0, 0};
        for (int r = r0; r < r1; ++r) {
            const float* rowp = H + (size_t)r * ldh;
            for (int i = 0; i < nc; ++i) {
                float v = rowp[tid + i * 256];
                s[i] += v; s2[i] += v * v;
            }
        }
        for (int i = 0; i < nc; ++i) {
            atomicAdd(&sums[tid + i * 256], s[i]);
            atomicAdd(&sums[O + tid + i * 256], s2[i]);
        }
    }
}

// ---------------- BN finalize ----------------
__global__ void k_bn_finalize(const float* __restrict__ sums, const float* __restrict__ g,
                              const float* __restrict__ bta, int O, float invR,
                              float* __restrict__ ss) {
    int o = blockIdx.x * 256 + threadIdx.x;
    if (o >= O) return;
    float mu = sums[o] * invR;
    float var = sums[O + o] * invR - mu * mu;
    float sc = g[o] / sqrtf(var + 1e-5f);
    ss[o] = sc;
    ss[O + o] = bta[o] - mu * sc;
}

// ---------------- graph_feature ----------------
__global__ __launch_bounds__(256) void k_graph_feature(
    const float* __restrict__ hT, int ldh, int C,
    const int* __restrict__ idx, const float* __restrict__ ss,
    float* __restrict__ out, int ldo, int colOff)
{
    int ppb = 256 / C;
    int p = threadIdx.x / C;
    int c = threadIdx.x % C;
    int r = blockIdx.x * ppb + p;
    int b = r >> 10;
    float sc = ss[c], sh = ss[C + c];
    float self = hT[(size_t)r * ldh + c];
    float vs = lrelu(sc * self + sh);
    const int* ip = idx + (size_t)r * KNN;
    float m = -FLT_MAX;
#pragma unroll 4
    for (int k = 0; k < KNN; ++k) {
        int j = ip[k];
        float hv = hT[((size_t)b * NPTS + j) * ldh + c];
        float v = lrelu(sc * hv + sh);
        m = fmaxf(m, v);
    }
    float* orow = out + (size_t)r * ldo + colOff;
    orow[c] = vs;
    orow[C + c] = m - vs;
}

// ---------------- channel max for conv5 ----------------
__global__ __launch_bounds__(256) void k_chanmax(const float* __restrict__ h5,
                                                 const float* __restrict__ ss,
                                                 float* __restrict__ feat) {
    int r = blockIdx.x;
    int tid = threadIdx.x;
    __shared__ float red[256];
    const float* rowp = h5 + (size_t)r * 1024;
    float m = -FLT_MAX;
    for (int o = tid; o < 1024; o += 256) {
        float v = lrelu(ss[o] * rowp[o] + ss[1024 + o]);
        m = fmaxf(m, v);
    }
    red[tid] = m;
    __syncthreads();
    for (int s = 128; s > 0; s >>= 1) {
        if (tid < s) red[tid] = fmaxf(red[tid], red[tid + s]);
        __syncthreads();
    }
    if (tid == 0) feat[r] = red[0];
}

// ---------------- FC ----------------
__global__ void k_fc(const float* __restrict__ in, const float* __restrict__ Lw,
                     const float* __restrict__ bias, float* __restrict__ out, int K, int J) {
    int g = blockIdx.x * 256 + threadIdx.x;
    if (g >= 32 * J) return;
    int b = g / J, j = g % J;
    const float* xr = in + (size_t)b * K;
    const float* wr = Lw + (size_t)j * K;
    float acc = 0.f;
    for (int k = 0; k < K; ++k) acc = fmaf(xr[k], wr[k], acc);
    out[g] = bias ? acc + bias[j] : acc;
}

// ---------------- BN1d over batch (32) + lrelu, in place ----------------
__global__ void k_bn1d(float* __restrict__ h, const float* __restrict__ g,
                       const float* __restrict__ bta, int J) {
    int j = blockIdx.x * 256 + threadIdx.x;
    if (j >= J) return;
    float s = 0.f, s2 = 0.f;
    for (int b = 0; b < 32; ++b) {
        float v = h[b * J + j];
        s += v; s2 += v * v;
    }
    float mu = s / 32.f;
    float var = s2 / 32.f - mu * mu;
    float sc = g[j] / sqrtf(var + 1e-5f);
    float sh = bta[j] - mu * sc;
    for (int b = 0; b < 32; ++b) {
        float v = sc * h[b * J + j] + sh;
        h[b * J + j] = lrelu(v);
    }
}

extern "C" void kernel_launch(void* const* d_in, const int* in_sizes, int n_in,
                              void* d_out, int out_size, void* d_ws, size_t ws_size,
                              hipStream_t stream) {
    const float* x   = (const float*)d_in[0];
    const float* W1  = (const float*)d_in[1];
    const float* g1  = (const float*)d_in[2];
    const float* b1  = (const float*)d_in[3];
    const float* W2  = (const float*)d_in[4];
    const float* g2  = (const float*)d_in[5];
    const float* b2  = (const float*)d_in[6];
    const float* W3  = (const float*)d_in[7];
    const float* g3  = (const float*)d_in[8];
    const float* b3  = (const float*)d_in[9];
    const float* W4  = (const float*)d_in[10];
    const float* g4  = (const float*)d_in[11];
    const float* b4  = (const float*)d_in[12];
    const float* W5  = (const float*)d_in[13];
    const float* g5  = (const float*)d_in[14];
    const float* b5  = (const float*)d_in[15];
    const float* L1  = (const float*)d_in[16];
    const float* g6  = (const float*)d_in[17];
    const float* b6  = (const float*)d_in[18];
    const float* L2  = (const float*)d_in[19];
    const float* bl2 = (const float*)d_in[20];
    const float* g7  = (const float*)d_in[21];
    const float* b7  = (const float*)d_in[22];
    const float* L3  = (const float*)d_in[23];
    const float* bl3 = (const float*)d_in[24];

    float* ws = (float*)d_ws;
    size_t off = 0;
    auto alloc = [&](size_t n) { size_t o = off; off += (n + 63) & ~(size_t)63; return o; };
    float* pd   = ws + alloc((size_t)NB * NPTS * NPTS);  // 134 MB, aliased with h5
    float* h5   = pd;
    float* xcT  = ws + alloc((size_t)RTOT * 640);
    float* hbuf = ws + alloc((size_t)RTOT * 128);
    float* xT   = ws + alloc((size_t)RTOT * 3);
    float* xxb  = ws + alloc(RTOT);
    float* sumsA = ws + alloc(2048 * 5);   // arena: conv1..4 + gemm5 stats, zeroed once
    float* ss   = ws + alloc(2048);
    float* feat = ws + alloc(RTOT);
    float* h1   = ws + alloc(32 * 512);
    float* h2   = ws + alloc(32 * 256);
    int*   idxb = (int*)(ws + alloc((size_t)RTOT * KNN));
    ushort* W5h = (ushort*)(ws + alloc(1024 * 640 / 2));
    ushort* W5l = (ushort*)(ws + alloc(1024 * 640 / 2));

    k_transpose_x<<<(NB * 3 * NPTS + 255) / 256, 256, 0, stream>>>(x, xT);
    k_split<<<(1024 * 640 / 8 + 255) / 256, 256, 0, stream>>>(W5, W5h, W5l, 1024 * 640);
    hipMemsetAsync(sumsA, 0, 2048 * 5 * sizeof(float), stream);

    auto run_knn = [&](const float* X, int ldx, int C) {
        k_xx<<<(RTOT + 255) / 256, 256, 0, stream>>>(X, ldx, C, xxb);
        if (C == 3)
            k_pd_sym<3><<<dim3(36, NB), 256, 0, stream>>>(X, ldx, xxb, pd);
        else
            k_pd_sym<128><<<dim3(36, NB), 256, 0, stream>>>(X, ldx, xxb, pd);
        k_topk_wave<<<RTOT / 4, 256, 0, stream>>>(pd, idxb);
    };
    auto run_conv = [&](const float* X, int ldx, int K, const float* W,
                        const float* g, const float* bta, int O, float* sums) {
        k_gemm_xwt<<<dim3(O / 64, RTOT / 64), 256, 0, stream>>>(X, ldx, K, W, hbuf, O);
        k_bn_stats<<<256, 256, 0, stream>>>(hbuf, O, O, RTOT, sums);
        k_bn_finalize<<<(O + 255) / 256, 256, 0, stream>>>(sums, g, bta, O, 1.f / RTOT, ss);
    };
    auto run_gf = [&](int C, int colOff) {
        int ppb = 256 / C;
        k_graph_feature<<<RTOT / ppb, 256, 0, stream>>>(hbuf, C, C, idxb, ss, xcT, 640, colOff);
    };

    // stage 1
    run_knn(xT, 3, 3);
    run_conv(xT, 3, 3, W1, g1, b1, 64, sumsA);
    run_gf(64, 0);

    // stage 2
    run_knn(xcT + 0, 640, 128);
    run_conv(xcT + 0, 640, 128, W2, g2, b2, 64, sumsA + 2048);
    run_gf(64, 128);

    // stage 3
    run_knn(xcT + 128, 640, 128);
    run_conv(xcT + 128, 640, 128, W3, g3, b3, 64, sumsA + 4096);
    run_gf(64, 256);

    // stage 4
    run_knn(xcT + 256, 640, 128);
    run_conv(xcT + 256, 640, 128, W4, g4, b4, 128, sumsA + 6144);
    run_gf(128, 384);

    // conv5 (BN fused into epilogue) + chan-max; 128x256 tiles, 1024 blocks, 512 threads
    float* sums5 = sumsA + 8192;
    k_gemm5_mfma<<<1024, 512, 0, stream>>>(xcT, W5h, W5l, h5, sums5);
    k_bn_finalize<<<4, 256, 0, stream>>>(sums5, g5, b5, 1024, 1.f / RTOT, ss);
    k_chanmax<<<RTOT, 256, 0, stream>>>(h5, ss, feat);

    // FC head
    k_fc<<<(32 * 512 + 255) / 256, 256, 0, stream>>>(feat, L1, nullptr, h1, 1024, 512);
    k_bn1d<<<(512 + 255) / 256, 256, 0, stream>>>(h1, g6, b6, 512);
    k_fc<<<(32 * 256 + 255) / 256, 256, 0, stream>>>(h1, L2, bl2, h2, 512, 256);
    k_bn1d<<<(256 + 255) / 256, 256, 0, stream>>>(h2, g7, b7, 256);
    k_fc<<<(32 * 40 + 255) / 256, 256, 0, stream>>>(h2, L3, bl3, (float*)d_out, 256, 40);
}

// Round 10
// 1644.911 us; speedup vs baseline: 1.0697x; 1.0101x over previous
//
#include <hip/hip_runtime.h>
#include <cfloat>
#include <cstdint>

#define NB 32
#define NPTS 1024
#define KNN 20
#define RTOT (NB * NPTS)

typedef __attribute__((ext_vector_type(8))) short bf16x8;
typedef __attribute__((ext_vector_type(4))) float f32x4;

__device__ __forceinline__ float lrelu(float v) { return v >= 0.f ? v : 0.2f * v; }

// ================= split-bf16 helpers =================
__device__ __forceinline__ void split2(float x, ushort& h, ushort& l) {
    uint u = __float_as_uint(x);
    uint r = u + 0x7FFFu + ((u >> 16) & 1u);
    ushort hh = (ushort)(r >> 16);
    float hf = __uint_as_float((uint)hh << 16);
    float d = x - hf;
    uint u2 = __float_as_uint(d);
    uint r2 = u2 + 0x7FFFu + ((u2 >> 16) & 1u);
    h = hh;
    l = (ushort)(r2 >> 16);
}

__device__ __forceinline__ uint pack2(ushort a, ushort b) { return (uint)a | ((uint)b << 16); }

__device__ __forceinline__ void stage_split8(const float* __restrict__ g,
                                             ushort* __restrict__ dh, ushort* __restrict__ dl) {
    float4 a = *(const float4*)(g);
    float4 b = *(const float4*)(g + 4);
    float xs[8] = {a.x, a.y, a.z, a.w, b.x, b.y, b.z, b.w};
    ushort h[8], l[8];
#pragma unroll
    for (int i = 0; i < 8; ++i) split2(xs[i], h[i], l[i]);
    uint4 H, L;
    H.x = pack2(h[0], h[1]); H.y = pack2(h[2], h[3]);
    H.z = pack2(h[4], h[5]); H.w = pack2(h[6], h[7]);
    L.x = pack2(l[0], l[1]); L.y = pack2(l[2], l[3]);
    L.z = pack2(l[4], l[5]); L.w = pack2(l[6], l[7]);
    *(uint4*)(dh) = H;
    *(uint4*)(dl) = L;
}

// ---------------- prep: transpose x | split W5 | zero sums arena (one dispatch) ----------------
__global__ void k_prep(const float* __restrict__ x, float* __restrict__ xT,
                       const float* __restrict__ W5, ushort* __restrict__ W5h,
                       ushort* __restrict__ W5l, float* __restrict__ sumsA) {
    int bid = blockIdx.x;
    if (bid < 384) {                    // transpose (B,3,N) -> (B*N,3): 384*256 == 32*3*1024
        int g = bid * 256 + threadIdx.x;
        int n = g % NPTS;
        int c = (g / NPTS) % 3;
        int b = g / (3 * NPTS);
        xT[((size_t)b * NPTS + n) * 3 + c] = x[g];
    } else if (bid < 704) {             // split W5: 320 blocks * 256 thr * 8 == 1024*640
        int g = ((bid - 384) * 256 + threadIdx.x) * 8;
        stage_split8(W5 + g, W5h + g, W5l + g);
    } else {                            // zero 5*2048 stats arena
        for (int i = threadIdx.x; i < 2048 * 5; i += 256) sumsA[i] = 0.f;
    }
}

// ---------------- 64x64 GEMM (small convs): H[r,o] = sum_k X[r,k]*W[o,k] ----------------
__global__ __launch_bounds__(256) void k_gemm_xwt(
    const float* __restrict__ X, int ldx, int K,
    const float* __restrict__ W,
    float* __restrict__ H, int ldh)
{
    __shared__ float As[16][68];
    __shared__ float Bs[16][68];
    int tid = threadIdx.x;
    int tx = tid & 15, ty = tid >> 4;
    int c0 = blockIdx.x * 64;
    int r0 = blockIdx.y * 64;
    float acc[4][4] = {};
    int lr = tid >> 4, lk = tid & 15;
    for (int k0 = 0; k0 < K; k0 += 16) {
#pragma unroll
        for (int i = 0; i < 4; ++i) {
            int row = lr + i * 16;
            int kk = k0 + lk;
            float av = 0.f, bv = 0.f;
            if (kk < K) {
                av = X[(size_t)(r0 + row) * ldx + kk];
                bv = W[(size_t)(c0 + row) * K + kk];
            }
            As[lk][row] = av;
            Bs[lk][row] = bv;
        }
        __syncthreads();
#pragma unroll
        for (int k = 0; k < 16; ++k) {
            float4 a4 = *(const float4*)&As[k][ty * 4];
            float4 b4 = *(const float4*)&Bs[k][tx * 4];
            float av[4] = {a4.x, a4.y, a4.z, a4.w};
            float bv[4] = {b4.x, b4.y, b4.z, b4.w};
#pragma unroll
            for (int i = 0; i < 4; ++i)
#pragma unroll
                for (int j = 0; j < 4; ++j)
                    acc[i][j] = fmaf(av[i], bv[j], acc[i][j]);
        }
        __syncthreads();
    }
#pragma unroll
    for (int i = 0; i < 4; ++i) {
        float4 v = make_float4(acc[i][0], acc[i][1], acc[i][2], acc[i][3]);
        *(float4*)&H[(size_t)(r0 + ty * 4 + i) * ldh + c0 + tx * 4] = v;
    }
}

// ------- symmetric batched pd with fused xx, upper-triangle blocks, 128x128 / 8x8 -------
// pd[b,n,m] = (2<Xn,Xm> - xx[n]) - xx[m]; xx recomputed per block (same serial k-order
// as the old k_xx -> bit-identical).
template<int K>
__global__ __launch_bounds__(256) void k_pd_sym(
    const float* __restrict__ X, int ldx, float* __restrict__ pd)
{
    __shared__ float As[16][132];
    __shared__ float Bs[16][132];
    __shared__ float sxr[128], sxc[128];
    int b = blockIdx.y;
    int tid = threadIdx.x;
    int tx = tid & 15, ty = tid >> 4;
    int t = blockIdx.x, rb = 0, rem = 8;
    while (t >= rem) { t -= rem; ++rb; --rem; }
    int cb = rb + t;
    int r0 = rb * 128, c0 = cb * 128;
    const float* Xb = X + (size_t)b * NPTS * ldx;
    // fused xx: thread t<128 -> row r0+t ; else col c0+(t-128). Serial k, same order as k_xx.
    {
        int rr = (tid < 128) ? (r0 + tid) : (c0 + tid - 128);
        const float* p = Xb + (size_t)rr * ldx;
        float s = 0.f;
#pragma unroll 8
        for (int c = 0; c < K; ++c) { float v = p[c]; s += v * v; }
        if (tid < 128) sxr[tid] = s; else sxc[tid - 128] = s;
    }
    int lk = tid & 15, lr = tid >> 4;
    float acc[8][8] = {};
    for (int k0 = 0; k0 < K; k0 += 16) {
#pragma unroll
        for (int i = 0; i < 8; ++i) {
            int row = lr + i * 16;
            int kk = k0 + lk;
            float av = 0.f, bv = 0.f;
            if (kk < K) {
                av = Xb[(size_t)(r0 + row) * ldx + kk];
                bv = Xb[(size_t)(c0 + row) * ldx + kk];
            }
            As[lk][row] = av;
            Bs[lk][row] = bv;
        }
        __syncthreads();
#pragma unroll
        for (int k = 0; k < 16; ++k) {
            float a[8], bb[8];
            *(float4*)&a[0]  = *(const float4*)&As[k][ty * 4];
            *(float4*)&a[4]  = *(const float4*)&As[k][64 + ty * 4];
            *(float4*)&bb[0] = *(const float4*)&Bs[k][tx * 4];
            *(float4*)&bb[4] = *(const float4*)&Bs[k][64 + tx * 4];
#pragma unroll
            for (int i = 0; i < 8; ++i)
#pragma unroll
                for (int j = 0; j < 8; ++j)
                    acc[i][j] = fmaf(a[i], bb[j], acc[i][j]);
        }
        __syncthreads();
    }
    float* pdb = pd + (size_t)b * NPTS * NPTS;
    float xc[8];
#pragma unroll
    for (int j = 0; j < 8; ++j)
        xc[j] = sxc[(j < 4) ? (tx * 4 + j) : (64 + tx * 4 + j - 4)];
    float xr[8];
#pragma unroll
    for (int i = 0; i < 8; ++i)
        xr[i] = sxr[(i < 4) ? (ty * 4 + i) : (64 + ty * 4 + i - 4)];
#pragma unroll
    for (int i = 0; i < 8; ++i) {
        int r = r0 + ((i < 4) ? (ty * 4 + i) : (64 + ty * 4 + i - 4));
        float* orow = &pdb[(size_t)r * NPTS + c0];
        float4 v0, v1;
        v0.x = 2.f * acc[i][0] - xr[i] - xc[0];
        v0.y = 2.f * acc[i][1] - xr[i] - xc[1];
        v0.z = 2.f * acc[i][2] - xr[i] - xc[2];
        v0.w = 2.f * acc[i][3] - xr[i] - xc[3];
        v1.x = 2.f * acc[i][4] - xr[i] - xc[4];
        v1.y = 2.f * acc[i][5] - xr[i] - xc[5];
        v1.z = 2.f * acc[i][6] - xr[i] - xc[6];
        v1.w = 2.f * acc[i][7] - xr[i] - xc[7];
        *(float4*)&orow[tx * 4]      = v0;
        *(float4*)&orow[64 + tx * 4] = v1;
    }
    if (cb > rb) {
#pragma unroll
        for (int j = 0; j < 8; ++j) {
            int c = c0 + ((j < 4) ? (tx * 4 + j) : (64 + tx * 4 + j - 4));
            float* orow = &pdb[(size_t)c * NPTS + r0];
            float4 w0, w1;
            w0.x = 2.f * acc[0][j] - xc[j] - xr[0];
            w0.y = 2.f * acc[1][j] - xc[j] - xr[1];
            w0.z = 2.f * acc[2][j] - xc[j] - xr[2];
            w0.w = 2.f * acc[3][j] - xc[j] - xr[3];
            w1.x = 2.f * acc[4][j] - xc[j] - xr[4];
            w1.y = 2.f * acc[5][j] - xc[j] - xr[5];
            w1.z = 2.f * acc[6][j] - xc[j] - xr[6];
            w1.w = 2.f * acc[7][j] - xc[j] - xr[7];
            *(float4*)&orow[ty * 4]      = w0;
            *(float4*)&orow[64 + ty * 4] = w1;
        }
    }
}

// ---------------- wave-per-row top-k (k=20), ties -> smaller index ----------------
__global__ __launch_bounds__(256) void k_topk_wave(const float* __restrict__ pd, int* __restrict__ idx) {
    int wid = (blockIdx.x * 256 + threadIdx.x) >> 6;
    int lane = threadIdx.x & 63;
    const float* row = pd + (size_t)wid * NPTS;
    float v[16];
#pragma unroll
    for (int j = 0; j < 16; ++j) v[j] = row[lane + 64 * j];
    float bv = v[0]; int bj = 0;
#pragma unroll
    for (int j = 1; j < 16; ++j) if (v[j] > bv) { bv = v[j]; bj = j; }
    int* out = idx + (size_t)wid * KNN;
    for (int kk = 0; kk < KNN; ++kk) {
        float cv = bv;
        int ci = lane + (bj << 6);
#pragma unroll
        for (int s = 1; s < 64; s <<= 1) {
            float ov = __shfl_xor(cv, s);
            int oi = __shfl_xor(ci, s);
            if (ov > cv || (ov == cv && oi < ci)) { cv = ov; ci = oi; }
        }
        if (lane == 0) out[kk] = ci;
        bool mine = (ci & 63) == lane;
        int jdead = ci >> 6;
#pragma unroll
        for (int j = 0; j < 16; ++j) if (mine && j == jdead) v[j] = -FLT_MAX;
        bv = v[0]; bj = 0;
#pragma unroll
        for (int j = 1; j < 16; ++j) if (v[j] > bv) { bv = v[j]; bj = j; }
    }
}

// conv5 GEMM: 128x256 block tile, 512 threads = 8 waves (2x4) of 64x64,
// mfma_f32_16x16x32_bf16, 3-pass hi/lo. XCD-chunked grid. BN stats fused.
#define LDK 40
__global__ __launch_bounds__(512) void k_gemm5_mfma(
    const float* __restrict__ X, const ushort* __restrict__ Wh, const ushort* __restrict__ Wl,
    float* __restrict__ H, float* __restrict__ sums)
{
    __shared__ __align__(16) ushort sAh[128 * LDK];
    __shared__ __align__(16) ushort sAl[128 * LDK];
    __shared__ __align__(16) ushort sBh[256 * LDK];
    __shared__ __align__(16) ushort sBl[256 * LDK];
    int tid = threadIdx.x;
    int lane = tid & 63, w = tid >> 6;
    int wm = w >> 2, wn = w & 3;
    int bid = blockIdx.x;
    int wg = (bid & 7) * 128 + (bid >> 3);
    int cb = wg & 3, rb = wg >> 2;
    int r0 = rb * 128, c0 = cb * 256;
    int srA = tid >> 2, skA = (tid & 3) * 8;
    int srB = tid >> 1, skB = (tid & 1) * 16;
    int fr = lane & 15;
    int kg = (lane >> 4) << 3;
    f32x4 acc[4][4] = {};
    for (int k0 = 0; k0 < 640; k0 += 32) {
        stage_split8(X + (size_t)(r0 + srA) * 640 + k0 + skA,
                     &sAh[srA * LDK + skA], &sAl[srA * LDK + skA]);
        {
            size_t gb = (size_t)(c0 + srB) * 640 + k0 + skB;
            *(uint4*)&sBh[srB * LDK + skB]     = *(const uint4*)(Wh + gb);
            *(uint4*)&sBh[srB * LDK + skB + 8] = *(const uint4*)(Wh + gb + 8);
            *(uint4*)&sBl[srB * LDK + skB]     = *(const uint4*)(Wl + gb);
            *(uint4*)&sBl[srB * LDK + skB + 8] = *(const uint4*)(Wl + gb + 8);
        }
        __syncthreads();
        bf16x8 ah[4], al[4];
#pragma unroll
        for (int mi = 0; mi < 4; ++mi) {
            int rr = wm * 64 + mi * 16 + fr;
            ah[mi] = *(const bf16x8*)&sAh[rr * LDK + kg];
            al[mi] = *(const bf16x8*)&sAl[rr * LDK + kg];
        }
#pragma unroll
        for (int ni = 0; ni < 4; ++ni) {
            int cc = wn * 64 + ni * 16 + fr;
            bf16x8 bh = *(const bf16x8*)&sBh[cc * LDK + kg];
            bf16x8 bl = *(const bf16x8*)&sBl[cc * LDK + kg];
#pragma unroll
            for (int mi = 0; mi < 4; ++mi) {
                acc[mi][ni] = __builtin_amdgcn_mfma_f32_16x16x32_bf16(ah[mi], bh, acc[mi][ni], 0, 0, 0);
                acc[mi][ni] = __builtin_amdgcn_mfma_f32_16x16x32_bf16(ah[mi], bl, acc[mi][ni], 0, 0, 0);
                acc[mi][ni] = __builtin_amdgcn_mfma_f32_16x16x32_bf16(al[mi], bh, acc[mi][ni], 0, 0, 0);
            }
        }
        __syncthreads();
    }
#pragma unroll
    for (int mi = 0; mi < 4; ++mi) {
        int rg = r0 + wm * 64 + mi * 16 + (lane >> 4) * 4;
#pragma unroll
        for (int ni = 0; ni < 4; ++ni) {
            int cg = c0 + wn * 64 + ni * 16 + fr;
#pragma unroll
            for (int r = 0; r < 4; ++r)
                H[(size_t)(rg + r) * 1024 + cg] = acc[mi][ni][r];
        }
    }
    float* csum  = (float*)sAh;
    float* csum2 = csum + 256;
    if (tid < 256) { csum[tid] = 0.f; csum2[tid] = 0.f; }
    __syncthreads();
#pragma unroll
    for (int ni = 0; ni < 4; ++ni) {
        float s = 0.f, s2 = 0.f;
#pragma unroll
        for (int mi = 0; mi < 4; ++mi)
#pragma unroll
            for (int r = 0; r < 4; ++r) { float v = acc[mi][ni][r]; s += v; s2 += v * v; }
        int c = wn * 64 + ni * 16 + fr;
        atomicAdd(&csum[c], s);
        atomicAdd(&csum2[c], s2);
    }
    __syncthreads();
    if (tid < 256) {
        atomicAdd(&sums[c0 + tid], csum[tid]);
        atomicAdd(&sums[1024 + c0 + tid], csum2[tid]);
    }
}

// ---------------- BN stats (conv1-4) ----------------
__global__ __launch_bounds__(256) void k_bn_stats(const float* __restrict__ H, int ldh, int O, int R,
                                                  float* __restrict__ sums) {
    int nblk = gridDim.x;
    int rows = (R + nblk - 1) / nblk;
    int r0 = blockIdx.x * rows;
    int r1 = r0 + rows; if (r1 > R) r1 = R;
    int tid = threadIdx.x;
    int per = 256 / O;
    int c = tid % O;
    int rOff = tid / O;
    float s = 0.f, s2 = 0.f;
    for (int r = r0 + rOff; r < r1; r += per) {
        float v = H[(size_t)r * ldh + c];
        s += v; s2 += v * v;
    }
    __shared__ float ls[256], ls2[256];
    ls[tid] = s; ls2[tid] = s2;
    __syncthreads();
    for (int st = 128; st >= O; st >>= 1) {
        if (tid < st) { ls[tid] += ls[tid + st]; ls2[tid] += ls2[tid + st]; }
        __syncthreads();
    }
    if (tid < O) {
        atomicAdd(&sums[c], ls[tid]);
        atomicAdd(&sums[O + c], ls2[tid]);
    }
}

// ---------------- graph_feature with fused BN finalize ----------------
__global__ __launch_bounds__(256) void k_graph_feature(
    const float* __restrict__ hT, int ldh, int C,
    const int* __restrict__ idx, const float* __restrict__ sums,
    const float* __restrict__ g, const float* __restrict__ bta, float invR,
    float* __restrict__ out, int ldo, int colOff)
{
    __shared__ float sss[256];   // [C] scale, [C..2C) shift (2C <= 256)
    int tid = threadIdx.x;
    if (tid < C) {
        float mu = sums[tid] * invR;
        float var = sums[C + tid] * invR - mu * mu;
        float sc = g[tid] / sqrtf(var + 1e-5f);
        sss[tid] = sc;
        sss[C + tid] = bta[tid] - mu * sc;
    }
    __syncthreads();
    int ppb = 256 / C;
    int p = tid / C;
    int c = tid % C;
    int r = blockIdx.x * ppb + p;
    int b = r >> 10;
    float sc = sss[c], sh = sss[C + c];
    float self = hT[(size_t)r * ldh + c];
    float vs = lrelu(sc * self + sh);
    const int* ip = idx + (size_t)r * KNN;
    float m = -FLT_MAX;
#pragma unroll 4
    for (int k = 0; k < KNN; ++k) {
        int j = ip[k];
        float hv = hT[((size_t)b * NPTS + j) * ldh + c];
        float v = lrelu(sc * hv + sh);
        m = fmaxf(m, v);
    }
    float* orow = out + (size_t)r * ldo + colOff;
    orow[c] = vs;
    orow[C + c] = m - vs;
}

// ---------------- channel max for conv5 with fused BN finalize; 8 rows/block ----------------
__global__ __launch_bounds__(256) void k_chanmax(const float* __restrict__ h5,
                                                 const float* __restrict__ sums,
                                                 const float* __restrict__ g,
                                                 const float* __restrict__ bta, float invR,
                                                 float* __restrict__ feat) {
    __shared__ float sls[2048];
    __shared__ float red[256];
    int tid = threadIdx.x;
    for (int o = tid; o < 1024; o += 256) {
        float mu = sums[o] * invR;
        float var = sums[1024 + o] * invR - mu * mu;
        float sc = g[o] / sqrtf(var + 1e-5f);
        sls[o] = sc;
        sls[1024 + o] = bta[o] - mu * sc;
    }
    __syncthreads();
    for (int rr = 0; rr < 8; ++rr) {
        int r = blockIdx.x * 8 + rr;
        const float* rowp = h5 + (size_t)r * 1024;
        float m = -FLT_MAX;
        for (int o = tid; o < 1024; o += 256) {
            float v = lrelu(sls[o] * rowp[o] + sls[1024 + o]);
            m = fmaxf(m, v);
        }
        red[tid] = m;
        __syncthreads();
        for (int s = 128; s > 0; s >>= 1) {
            if (tid < s) red[tid] = fmaxf(red[tid], red[tid + s]);
            __syncthreads();
        }
        if (tid == 0) feat[r] = red[0];
        __syncthreads();
    }
}

// ---------------- fused FC + BN1d + lrelu: 8 channels x 32 batches per block ----------------
__global__ __launch_bounds__(256) void k_fc_bn(
    const float* __restrict__ in, const float* __restrict__ Lw, const float* __restrict__ bias,
    const float* __restrict__ g, const float* __restrict__ bta,
    float* __restrict__ out, int K, int J)
{
    int tid = threadIdx.x;
    int b = tid & 31, jj = tid >> 5;
    int j = blockIdx.x * 8 + jj;
    const float* xr = in + (size_t)b * K;
    const float* wr = Lw + (size_t)j * K;
    float acc = 0.f;
    for (int k = 0; k < K; ++k) acc = fmaf(xr[k], wr[k], acc);
    if (bias) acc += bias[j];
    __shared__ float lh[8][33];
    __shared__ float lsc[8], lsh[8];
    lh[jj][b] = acc;
    __syncthreads();
    if (b == 0) {
        float s = 0.f, s2 = 0.f;
        for (int bb = 0; bb < 32; ++bb) { float v = lh[jj][bb]; s += v; s2 += v * v; }
        float mu = s / 32.f;
        float var = s2 / 32.f - mu * mu;
        float sc = g[j] / sqrtf(var + 1e-5f);
        lsc[jj] = sc;
        lsh[jj] = bta[j] - mu * sc;
    }
    __syncthreads();
    out[(size_t)b * J + j] = lrelu(lsc[jj] * acc + lsh[jj]);
}

// ---------------- final FC (no BN) ----------------
__global__ void k_fc(const float* __restrict__ in, const float* __restrict__ Lw,
                     const float* __restrict__ bias, float* __restrict__ out, int K, int J) {
    int g = blockIdx.x * 256 + threadIdx.x;
    if (g >= 32 * J) return;
    int b = g / J, j = g % J;
    const float* xr = in + (size_t)b * K;
    const float* wr = Lw + (size_t)j * K;
    float acc = 0.f;
    for (int k = 0; k < K; ++k) acc = fmaf(xr[k], wr[k], acc);
    out[g] = bias ? acc + bias[j] : acc;
}

extern "C" void kernel_launch(void* const* d_in, const int* in_sizes, int n_in,
                              void* d_out, int out_size, void* d_ws, size_t ws_size,
                              hipStream_t stream) {
    const float* x   = (const float*)d_in[0];
    const float* W1  = (const float*)d_in[1];
    const float* g1  = (const float*)d_in[2];
    const float* b1  = (const float*)d_in[3];
    const float* W2  = (const float*)d_in[4];
    const float* g2  = (const float*)d_in[5];
    const float* b2  = (const float*)d_in[6];
    const float* W3  = (const float*)d_in[7];
    const float* g3  = (const float*)d_in[8];
    const float* b3  = (const float*)d_in[9];
    const float* W4  = (const float*)d_in[10];
    const float* g4  = (const float*)d_in[11];
    const float* b4  = (const float*)d_in[12];
    const float* W5  = (const float*)d_in[13];
    const float* g5  = (const float*)d_in[14];
    const float* b5  = (const float*)d_in[15];
    const float* L1  = (const float*)d_in[16];
    const float* g6  = (const float*)d_in[17];
    const float* b6  = (const float*)d_in[18];
    const float* L2  = (const float*)d_in[19];
    const float* bl2 = (const float*)d_in[20];
    const float* g7  = (const float*)d_in[21];
    const float* b7  = (const float*)d_in[22];
    const float* L3  = (const float*)d_in[23];
    const float* bl3 = (const float*)d_in[24];

    float* ws = (float*)d_ws;
    size_t off = 0;
    auto alloc = [&](size_t n) { size_t o = off; off += (n + 63) & ~(size_t)63; return o; };
    float* pd   = ws + alloc((size_t)NB * NPTS * NPTS);  // 134 MB, aliased with h5
    float* h5   = pd;
    float* xcT  = ws + alloc((size_t)RTOT * 640);
    float* hbuf = ws + alloc((size_t)RTOT * 128);
    float* xT   = ws + alloc((size_t)RTOT * 3);
    float* sumsA = ws + alloc(2048 * 5);   // stats arena: conv1..4 + gemm5, zeroed in k_prep
    float* feat = ws + alloc(RTOT);
    float* h1   = ws + alloc(32 * 512);
    float* h2   = ws + alloc(32 * 256);
    int*   idxb = (int*)(ws + alloc((size_t)RTOT * KNN));
    ushort* W5h = (ushort*)(ws + alloc(1024 * 640 / 2));
    ushort* W5l = (ushort*)(ws + alloc(1024 * 640 / 2));
    const float invR = 1.f / RTOT;

    k_prep<<<705, 256, 0, stream>>>(x, xT, W5, W5h, W5l, sumsA);

    auto run_knn = [&](const float* X, int ldx, int C) {
        if (C == 3)
            k_pd_sym<3><<<dim3(36, NB), 256, 0, stream>>>(X, ldx, pd);
        else
            k_pd_sym<128><<<dim3(36, NB), 256, 0, stream>>>(X, ldx, pd);
        k_topk_wave<<<RTOT / 4, 256, 0, stream>>>(pd, idxb);
    };
    auto run_conv = [&](const float* X, int ldx, int K, const float* W, int O, float* sums) {
        k_gemm_xwt<<<dim3(O / 64, RTOT / 64), 256, 0, stream>>>(X, ldx, K, W, hbuf, O);
        k_bn_stats<<<256, 256, 0, stream>>>(hbuf, O, O, RTOT, sums);
    };
    auto run_gf = [&](int C, int colOff, const float* sums, const float* g, const float* bta) {
        int ppb = 256 / C;
        k_graph_feature<<<RTOT / ppb, 256, 0, stream>>>(hbuf, C, C, idxb, sums, g, bta, invR,
                                                        xcT, 640, colOff);
    };

    // stage 1
    run_knn(xT, 3, 3);
    run_conv(xT, 3, 3, W1, 64, sumsA);
    run_gf(64, 0, sumsA, g1, b1);

    // stage 2
    run_knn(xcT + 0, 640, 128);
    run_conv(xcT + 0, 640, 128, W2, 64, sumsA + 2048);
    run_gf(64, 128, sumsA + 2048, g2, b2);

    // stage 3
    run_knn(xcT + 128, 640, 128);
    run_conv(xcT + 128, 640, 128, W3, 64, sumsA + 4096);
    run_gf(64, 256, sumsA + 4096, g3, b3);

    // stage 4
    run_knn(xcT + 256, 640, 128);
    run_conv(xcT + 256, 640, 128, W4, 128, sumsA + 6144);
    run_gf(128, 384, sumsA + 6144, g4, b4);

    // conv5 (BN stats fused) + chan-max (BN finalize fused)
    float* sums5 = sumsA + 8192;
    k_gemm5_mfma<<<1024, 512, 0, stream>>>(xcT, W5h, W5l, h5, sums5);
    k_chanmax<<<RTOT / 8, 256, 0, stream>>>(h5, sums5, g5, b5, invR, feat);

    // FC head (fc+bn fused pairwise)
    k_fc_bn<<<64, 256, 0, stream>>>(feat, L1, nullptr, g6, b6, h1, 1024, 512);
    k_fc_bn<<<32, 256, 0, stream>>>(h1, L2, bl2, g7, b7, h2, 512, 256);
    k_fc<<<(32 * 40 + 255) / 256, 256, 0, stream>>>(h2, L3, bl3, (float*)d_out, 256, 40);
}

// Round 12
// 1599.151 us; speedup vs baseline: 1.1003x; 1.0286x over previous
//
#include <hip/hip_runtime.h>
#include <cfloat>
#include <cstdint>

#define NB 32
#define NPTS 1024
#define KNN 20
#define RTOT (NB * NPTS)

typedef __attribute__((ext_vector_type(8))) short bf16x8;
typedef __attribute__((ext_vector_type(4))) float f32x4;

__device__ __forceinline__ float lrelu(float v) { return v >= 0.f ? v : 0.2f * v; }

// ================= split-bf16 helpers =================
__device__ __forceinline__ void split2(float x, ushort& h, ushort& l) {
    uint u = __float_as_uint(x);
    uint r = u + 0x7FFFu + ((u >> 16) & 1u);
    ushort hh = (ushort)(r >> 16);
    float hf = __uint_as_float((uint)hh << 16);
    float d = x - hf;
    uint u2 = __float_as_uint(d);
    uint r2 = u2 + 0x7FFFu + ((u2 >> 16) & 1u);
    h = hh;
    l = (ushort)(r2 >> 16);
}

__device__ __forceinline__ uint pack2(ushort a, ushort b) { return (uint)a | ((uint)b << 16); }

__device__ __forceinline__ void stage_split8(const float* __restrict__ g,
                                             ushort* __restrict__ dh, ushort* __restrict__ dl) {
    float4 a = *(const float4*)(g);
    float4 b = *(const float4*)(g + 4);
    float xs[8] = {a.x, a.y, a.z, a.w, b.x, b.y, b.z, b.w};
    ushort h[8], l[8];
#pragma unroll
    for (int i = 0; i < 8; ++i) split2(xs[i], h[i], l[i]);
    uint4 H, L;
    H.x = pack2(h[0], h[1]); H.y = pack2(h[2], h[3]);
    H.z = pack2(h[4], h[5]); H.w = pack2(h[6], h[7]);
    L.x = pack2(l[0], l[1]); L.y = pack2(l[2], l[3]);
    L.z = pack2(l[4], l[5]); L.w = pack2(l[6], l[7]);
    *(uint4*)(dh) = H;
    *(uint4*)(dl) = L;
}

// ---------------- prep: transpose x | split W5 | zero sums arena (one dispatch) ----------------
__global__ void k_prep(const float* __restrict__ x, float* __restrict__ xT,
                       const float* __restrict__ W5, ushort* __restrict__ W5h,
                       ushort* __restrict__ W5l, float* __restrict__ sumsA) {
    int bid = blockIdx.x;
    if (bid < 384) {
        int g = bid * 256 + threadIdx.x;
        int n = g % NPTS;
        int c = (g / NPTS) % 3;
        int b = g / (3 * NPTS);
        xT[((size_t)b * NPTS + n) * 3 + c] = x[g];
    } else if (bid < 704) {
        int g = ((bid - 384) * 256 + threadIdx.x) * 8;
        stage_split8(W5 + g, W5h + g, W5l + g);
    } else {
        for (int i = threadIdx.x; i < 2048 * 5; i += 256) sumsA[i] = 0.f;
    }
}

// ---------------- 64x64 GEMM (small convs): H[r,o] = sum_k X[r,k]*W[o,k] ----------------
__global__ __launch_bounds__(256) void k_gemm_xwt(
    const float* __restrict__ X, int ldx, int K,
    const float* __restrict__ W,
    float* __restrict__ H, int ldh)
{
    __shared__ float As[16][68];
    __shared__ float Bs[16][68];
    int tid = threadIdx.x;
    int tx = tid & 15, ty = tid >> 4;
    int c0 = blockIdx.x * 64;
    int r0 = blockIdx.y * 64;
    float acc[4][4] = {};
    int lr = tid >> 4, lk = tid & 15;
    for (int k0 = 0; k0 < K; k0 += 16) {
#pragma unroll
        for (int i = 0; i < 4; ++i) {
            int row = lr + i * 16;
            int kk = k0 + lk;
            float av = 0.f, bv = 0.f;
            if (kk < K) {
                av = X[(size_t)(r0 + row) * ldx + kk];
                bv = W[(size_t)(c0 + row) * K + kk];
            }
            As[lk][row] = av;
            Bs[lk][row] = bv;
        }
        __syncthreads();
#pragma unroll
        for (int k = 0; k < 16; ++k) {
            float4 a4 = *(const float4*)&As[k][ty * 4];
            float4 b4 = *(const float4*)&Bs[k][tx * 4];
            float av[4] = {a4.x, a4.y, a4.z, a4.w};
            float bv[4] = {b4.x, b4.y, b4.z, b4.w};
#pragma unroll
            for (int i = 0; i < 4; ++i)
#pragma unroll
                for (int j = 0; j < 4; ++j)
                    acc[i][j] = fmaf(av[i], bv[j], acc[i][j]);
        }
        __syncthreads();
    }
#pragma unroll
    for (int i = 0; i < 4; ++i) {
        float4 v = make_float4(acc[i][0], acc[i][1], acc[i][2], acc[i][3]);
        *(float4*)&H[(size_t)(r0 + ty * 4 + i) * ldh + c0 + tx * 4] = v;
    }
}

// tile order: 28 off-diagonal tiles first, 8 diagonal tiles last (cheap blocks in the tail)
__constant__ int pd_tile_order[36] = {
    1, 2, 3, 4, 5, 6, 7,          // rb=0 off-diag
    9, 10, 11, 12, 13, 14,        // rb=1
    16, 17, 18, 19, 20,           // rb=2
    22, 23, 24, 25,               // rb=3
    27, 28, 29,                   // rb=4
    31, 32,                       // rb=5
    34,                           // rb=6
    0, 8, 15, 21, 26, 30, 33, 35  // diagonals
};

// ------- symmetric batched pd with fused xx, upper-triangle blocks, 128x128 / 8x8 -------
// 1D grid (tile-major, batch fastest) with diag tiles scheduled last.
template<int K>
__global__ __launch_bounds__(256) void k_pd_sym(
    const float* __restrict__ X, int ldx, float* __restrict__ pd)
{
    __shared__ float As[16][132];
    __shared__ float Bs[16][132];
    __shared__ float sxr[128], sxc[128];
    int b = blockIdx.x & 31;
    int t = pd_tile_order[blockIdx.x >> 5];
    int tid = threadIdx.x;
    int tx = tid & 15, ty = tid >> 4;
    int rb = 0, rem = 8;
    while (t >= rem) { t -= rem; ++rb; --rem; }
    int cb = rb + t;
    int r0 = rb * 128, c0 = cb * 128;
    const float* Xb = X + (size_t)b * NPTS * ldx;
    {
        int rr = (tid < 128) ? (r0 + tid) : (c0 + tid - 128);
        const float* p = Xb + (size_t)rr * ldx;
        float s = 0.f;
#pragma unroll 8
        for (int c = 0; c < K; ++c) { float v = p[c]; s += v * v; }
        if (tid < 128) sxr[tid] = s; else sxc[tid - 128] = s;
    }
    int lk = tid & 15, lr = tid >> 4;
    float acc[8][8] = {};
    for (int k0 = 0; k0 < K; k0 += 16) {
#pragma unroll
        for (int i = 0; i < 8; ++i) {
            int row = lr + i * 16;
            int kk = k0 + lk;
            float av = 0.f, bv = 0.f;
            if (kk < K) {
                av = Xb[(size_t)(r0 + row) * ldx + kk];
                bv = Xb[(size_t)(c0 + row) * ldx + kk];
            }
            As[lk][row] = av;
            Bs[lk][row] = bv;
        }
        __syncthreads();
#pragma unroll
        for (int k = 0; k < 16; ++k) {
            float a[8], bb[8];
            *(float4*)&a[0]  = *(const float4*)&As[k][ty * 4];
            *(float4*)&a[4]  = *(const float4*)&As[k][64 + ty * 4];
            *(float4*)&bb[0] = *(const float4*)&Bs[k][tx * 4];
            *(float4*)&bb[4] = *(const float4*)&Bs[k][64 + tx * 4];
#pragma unroll
            for (int i = 0; i < 8; ++i)
#pragma unroll
                for (int j = 0; j < 8; ++j)
                    acc[i][j] = fmaf(a[i], bb[j], acc[i][j]);
        }
        __syncthreads();
    }
    float* pdb = pd + (size_t)b * NPTS * NPTS;
    float xc[8];
#pragma unroll
    for (int j = 0; j < 8; ++j)
        xc[j] = sxc[(j < 4) ? (tx * 4 + j) : (64 + tx * 4 + j - 4)];
    float xr[8];
#pragma unroll
    for (int i = 0; i < 8; ++i)
        xr[i] = sxr[(i < 4) ? (ty * 4 + i) : (64 + ty * 4 + i - 4)];
#pragma unroll
    for (int i = 0; i < 8; ++i) {
        int r = r0 + ((i < 4) ? (ty * 4 + i) : (64 + ty * 4 + i - 4));
        float* orow = &pdb[(size_t)r * NPTS + c0];
        float4 v0, v1;
        v0.x = 2.f * acc[i][0] - xr[i] - xc[0];
        v0.y = 2.f * acc[i][1] - xr[i] - xc[1];
        v0.z = 2.f * acc[i][2] - xr[i] - xc[2];
        v0.w = 2.f * acc[i][3] - xr[i] - xc[3];
        v1.x = 2.f * acc[i][4] - xr[i] - xc[4];
        v1.y = 2.f * acc[i][5] - xr[i] - xc[5];
        v1.z = 2.f * acc[i][6] - xr[i] - xc[6];
        v1.w = 2.f * acc[i][7] - xr[i] - xc[7];
        *(float4*)&orow[tx * 4]      = v0;
        *(float4*)&orow[64 + tx * 4] = v1;
    }
    if (cb > rb) {
#pragma unroll
        for (int j = 0; j < 8; ++j) {
            int c = c0 + ((j < 4) ? (tx * 4 + j) : (64 + tx * 4 + j - 4));
            float* orow = &pdb[(size_t)c * NPTS + r0];
            float4 w0, w1;
            w0.x = 2.f * acc[0][j] - xc[j] - xr[0];
            w0.y = 2.f * acc[1][j] - xc[j] - xr[1];
            w0.z = 2.f * acc[2][j] - xc[j] - xr[2];
            w0.w = 2.f * acc[3][j] - xc[j] - xr[3];
            w1.x = 2.f * acc[4][j] - xc[j] - xr[4];
            w1.y = 2.f * acc[5][j] - xc[j] - xr[5];
            w1.z = 2.f * acc[6][j] - xc[j] - xr[6];
            w1.w = 2.f * acc[7][j] - xc[j] - xr[7];
            *(float4*)&orow[ty * 4]      = w0;
            *(float4*)&orow[64 + ty * 4] = w1;
        }
    }
}

// ---------------- wave-per-2-rows top-k (k=20), ILP over two independent reduce chains ----------------
// Tie rule per row: strict > keeps smallest j per lane; reduce prefers smaller index on equal
// value -> exactly jax top_k order. Bit-identical to the 1-row version.
__global__ __launch_bounds__(256) void k_topk_wave(const float* __restrict__ pd, int* __restrict__ idx) {
    int w = (blockIdx.x * 256 + threadIdx.x) >> 6;   // wave id in [0, RTOT/2)
    int lane = threadIdx.x & 63;
    const float* row0 = pd + (size_t)(2 * w) * NPTS;
    const float* row1 = row0 + NPTS;
    float v0[16], v1[16];
#pragma unroll
    for (int j = 0; j < 16; ++j) { v0[j] = row0[lane + 64 * j]; v1[j] = row1[lane + 64 * j]; }
    float bv0 = v0[0], bv1 = v1[0];
    int bj0 = 0, bj1 = 0;
#pragma unroll
    for (int j = 1; j < 16; ++j) {
        if (v0[j] > bv0) { bv0 = v0[j]; bj0 = j; }
        if (v1[j] > bv1) { bv1 = v1[j]; bj1 = j; }
    }
    int* out0 = idx + (size_t)(2 * w) * KNN;
    int* out1 = out0 + KNN;
    for (int kk = 0; kk < KNN; ++kk) {
        float cv0 = bv0, cv1 = bv1;
        int ci0 = lane + (bj0 << 6), ci1 = lane + (bj1 << 6);
#pragma unroll
        for (int s = 1; s < 64; s <<= 1) {
            float ov0 = __shfl_xor(cv0, s);
            int oi0 = __shfl_xor(ci0, s);
            float ov1 = __shfl_xor(cv1, s);
            int oi1 = __shfl_xor(ci1, s);
            if (ov0 > cv0 || (ov0 == cv0 && oi0 < ci0)) { cv0 = ov0; ci0 = oi0; }
            if (ov1 > cv1 || (ov1 == cv1 && oi1 < ci1)) { cv1 = ov1; ci1 = oi1; }
        }
        if (lane == 0) { out0[kk] = ci0; out1[kk] = ci1; }
        bool mine0 = (ci0 & 63) == lane;
        bool mine1 = (ci1 & 63) == lane;
        int jd0 = ci0 >> 6, jd1 = ci1 >> 6;
#pragma unroll
        for (int j = 0; j < 16; ++j) {
            if (mine0 && j == jd0) v0[j] = -FLT_MAX;
            if (mine1 && j == jd1) v1[j] = -FLT_MAX;
        }
        bv0 = v0[0]; bj0 = 0; bv1 = v1[0]; bj1 = 0;
#pragma unroll
        for (int j = 1; j < 16; ++j) {
            if (v0[j] > bv0) { bv0 = v0[j]; bj0 = j; }
            if (v1[j] > bv1) { bv1 = v1[j]; bj1 = j; }
        }
    }
}

// conv5 GEMM: 128x256 block tile, 512 threads = 8 waves (2x4) of 64x64,
// mfma_f32_16x16x32_bf16, 3-pass hi/lo. XCD-chunked grid. BN stats fused.
#define LDK 40
__global__ __launch_bounds__(512) void k_gemm5_mfma(
    const float* __restrict__ X, const ushort* __restrict__ Wh, const ushort* __restrict__ Wl,
    float* __restrict__ H, float* __restrict__ sums)
{
    __shared__ __align__(16) ushort sAh[128 * LDK];
    __shared__ __align__(16) ushort sAl[128 * LDK];
    __shared__ __align__(16) ushort sBh[256 * LDK];
    __shared__ __align__(16) ushort sBl[256 * LDK];
    int tid = threadIdx.x;
    int lane = tid & 63, w = tid >> 6;
    int wm = w >> 2, wn = w & 3;
    int bid = blockIdx.x;
    int wg = (bid & 7) * 128 + (bid >> 3);
    int cb = wg & 3, rb = wg >> 2;
    int r0 = rb * 128, c0 = cb * 256;
    int srA = tid >> 2, skA = (tid & 3) * 8;
    int srB = tid >> 1, skB = (tid & 1) * 16;
    int fr = lane & 15;
    int kg = (lane >> 4) << 3;
    f32x4 acc[4][4] = {};
    for (int k0 = 0; k0 < 640; k0 += 32) {
        stage_split8(X + (size_t)(r0 + srA) * 640 + k0 + skA,
                     &sAh[srA * LDK + skA], &sAl[srA * LDK + skA]);
        {
            size_t gb = (size_t)(c0 + srB) * 640 + k0 + skB;
            *(uint4*)&sBh[srB * LDK + skB]     = *(const uint4*)(Wh + gb);
            *(uint4*)&sBh[srB * LDK + skB + 8] = *(const uint4*)(Wh + gb + 8);
            *(uint4*)&sBl[srB * LDK + skB]     = *(const uint4*)(Wl + gb);
            *(uint4*)&sBl[srB * LDK + skB + 8] = *(const uint4*)(Wl + gb + 8);
        }
        __syncthreads();
        bf16x8 ah[4], al[4];
#pragma unroll
        for (int mi = 0; mi < 4; ++mi) {
            int rr = wm * 64 + mi * 16 + fr;
            ah[mi] = *(const bf16x8*)&sAh[rr * LDK + kg];
            al[mi] = *(const bf16x8*)&sAl[rr * LDK + kg];
        }
#pragma unroll
        for (int ni = 0; ni < 4; ++ni) {
            int cc = wn * 64 + ni * 16 + fr;
            bf16x8 bh = *(const bf16x8*)&sBh[cc * LDK + kg];
            bf16x8 bl = *(const bf16x8*)&sBl[cc * LDK + kg];
#pragma unroll
            for (int mi = 0; mi < 4; ++mi) {
                acc[mi][ni] = __builtin_amdgcn_mfma_f32_16x16x32_bf16(ah[mi], bh, acc[mi][ni], 0, 0, 0);
                acc[mi][ni] = __builtin_amdgcn_mfma_f32_16x16x32_bf16(ah[mi], bl, acc[mi][ni], 0, 0, 0);
                acc[mi][ni] = __builtin_amdgcn_mfma_f32_16x16x32_bf16(al[mi], bh, acc[mi][ni], 0, 0, 0);
            }
        }
        __syncthreads();
    }
#pragma unroll
    for (int mi = 0; mi < 4; ++mi) {
        int rg = r0 + wm * 64 + mi * 16 + (lane >> 4) * 4;
#pragma unroll
        for (int ni = 0; ni < 4; ++ni) {
            int cg = c0 + wn * 64 + ni * 16 + fr;
#pragma unroll
            for (int r = 0; r < 4; ++r)
                H[(size_t)(rg + r) * 1024 + cg] = acc[mi][ni][r];
        }
    }
    float* csum  = (float*)sAh;
    float* csum2 = csum + 256;
    if (tid < 256) { csum[tid] = 0.f; csum2[tid] = 0.f; }
    __syncthreads();
#pragma unroll
    for (int ni = 0; ni < 4; ++ni) {
        float s = 0.f, s2 = 0.f;
#pragma unroll
        for (int mi = 0; mi < 4; ++mi)
#pragma unroll
            for (int r = 0; r < 4; ++r) { float v = acc[mi][ni][r]; s += v; s2 += v * v; }
        int c = wn * 64 + ni * 16 + fr;
        atomicAdd(&csum[c], s);
        atomicAdd(&csum2[c], s2);
    }
    __syncthreads();
    if (tid < 256) {
        atomicAdd(&sums[c0 + tid], csum[tid]);
        atomicAdd(&sums[1024 + c0 + tid], csum2[tid]);
    }
}

// ---------------- BN stats (conv1-4) ----------------
__global__ __launch_bounds__(256) void k_bn_stats(const float* __restrict__ H, int ldh, int O, int R,
                                                  float* __restrict__ sums) {
    int nblk = gridDim.x;
    int rows = (R + nblk - 1) / nblk;
    int r0 = blockIdx.x * rows;
    int r1 = r0 + rows; if (r1 > R) r1 = R;
    int tid = threadIdx.x;
    int per = 256 / O;
    int c = tid % O;
    int rOff = tid / O;
    float s = 0.f, s2 = 0.f;
    for (int r = r0 + rOff; r < r1; r += per) {
        float v = H[(size_t)r * ldh + c];
        s += v; s2 += v * v;
    }
    __shared__ float ls[256], ls2[256];
    ls[tid] = s; ls2[tid] = s2;
    __syncthreads();
    for (int st = 128; st >= O; st >>= 1) {
        if (tid < st) { ls[tid] += ls[tid + st]; ls2[tid] += ls2[tid + st]; }
        __syncthreads();
    }
    if (tid < O) {
        atomicAdd(&sums[c], ls[tid]);
        atomicAdd(&sums[O + c], ls2[tid]);
    }
}

// ---------------- graph_feature with fused BN finalize ----------------
__global__ __launch_bounds__(256) void k_graph_feature(
    const float* __restrict__ hT, int ldh, int C,
    const int* __restrict__ idx, const float* __restrict__ sums,
    const float* __restrict__ g, const float* __restrict__ bta, float invR,
    float* __restrict__ out, int ldo, int colOff)
{
    __shared__ float sss[256];
    int tid = threadIdx.x;
    if (tid < C) {
        float mu = sums[tid] * invR;
        float var = sums[C + tid] * invR - mu * mu;
        float sc = g[tid] / sqrtf(var + 1e-5f);
        sss[tid] = sc;
        sss[C + tid] = bta[tid] - mu * sc;
    }
    __syncthreads();
    int ppb = 256 / C;
    int p = tid / C;
    int c = tid % C;
    int r = blockIdx.x * ppb + p;
    int b = r >> 10;
    float sc = sss[c], sh = sss[C + c];
    float self = hT[(size_t)r * ldh + c];
    float vs = lrelu(sc * self + sh);
    const int* ip = idx + (size_t)r * KNN;
    float m = -FLT_MAX;
#pragma unroll 4
    for (int k = 0; k < KNN; ++k) {
        int j = ip[k];
        float hv = hT[((size_t)b * NPTS + j) * ldh + c];
        float v = lrelu(sc * hv + sh);
        m = fmaxf(m, v);
    }
    float* orow = out + (size_t)r * ldo + colOff;
    orow[c] = vs;
    orow[C + c] = m - vs;
}

// ---------------- channel max for conv5 with fused BN finalize; 8 rows/block ----------------
__global__ __launch_bounds__(256) void k_chanmax(const float* __restrict__ h5,
                                                 const float* __restrict__ sums,
                                                 const float* __restrict__ g,
                                                 const float* __restrict__ bta, float invR,
                                                 float* __restrict__ feat) {
    __shared__ float sls[2048];
    __shared__ float red[256];
    int tid = threadIdx.x;
    for (int o = tid; o < 1024; o += 256) {
        float mu = sums[o] * invR;
        float var = sums[1024 + o] * invR - mu * mu;
        float sc = g[o] / sqrtf(var + 1e-5f);
        sls[o] = sc;
        sls[1024 + o] = bta[o] - mu * sc;
    }
    __syncthreads();
    for (int rr = 0; rr < 8; ++rr) {
        int r = blockIdx.x * 8 + rr;
        const float* rowp = h5 + (size_t)r * 1024;
        float m = -FLT_MAX;
        for (int o = tid; o < 1024; o += 256) {
            float v = lrelu(sls[o] * rowp[o] + sls[1024 + o]);
            m = fmaxf(m, v);
        }
        red[tid] = m;
        __syncthreads();
        for (int s = 128; s > 0; s >>= 1) {
            if (tid < s) red[tid] = fmaxf(red[tid], red[tid + s]);
            __syncthreads();
        }
        if (tid == 0) feat[r] = red[0];
        __syncthreads();
    }
}

// ---------------- fused FC + BN1d + lrelu: 8 channels x 32 batches per block ----------------
__global__ __launch_bounds__(256) void k_fc_bn(
    const float* __restrict__ in, const float* __restrict__ Lw, const float* __restrict__ bias,
    const float* __restrict__ g, const float* __restrict__ bta,
    float* __restrict__ out, int K, int J)
{
    int tid = threadIdx.x;
    int b = tid & 31, jj = tid >> 5;
    int j = blockIdx.x * 8 + jj;
    const float* xr = in + (size_t)b * K;
    const float* wr = Lw + (size_t)j * K;
    float acc = 0.f;
    for (int k = 0; k < K; ++k) acc = fmaf(xr[k], wr[k], acc);
    if (bias) acc += bias[j];
    __shared__ float lh[8][33];
    __shared__ float lsc[8], lsh[8];
    lh[jj][b] = acc;
    __syncthreads();
    if (b == 0) {
        float s = 0.f, s2 = 0.f;
        for (int bb = 0; bb < 32; ++bb) { float v = lh[jj][bb]; s += v; s2 += v * v; }
        float mu = s / 32.f;
        float var = s2 / 32.f - mu * mu;
        float sc = g[j] / sqrtf(var + 1e-5f);
        lsc[jj] = sc;
        lsh[jj] = bta[j] - mu * sc;
    }
    __syncthreads();
    out[(size_t)b * J + j] = lrelu(lsc[jj] * acc + lsh[jj]);
}

// ---------------- final FC (no BN) ----------------
__global__ void k_fc(const float* __restrict__ in, const float* __restrict__ Lw,
                     const float* __restrict__ bias, float* __restrict__ out, int K, int J) {
    int g = blockIdx.x * 256 + threadIdx.x;
    if (g >= 32 * J) return;
    int b = g / J, j = g % J;
    const float* xr = in + (size_t)b * K;
    const float* wr = Lw + (size_t)j * K;
    float acc = 0.f;
    for (int k = 0; k < K; ++k) acc = fmaf(xr[k], wr[k], acc);
    out[g] = bias ? acc + bias[j] : acc;
}

extern "C" void kernel_launch(void* const* d_in, const int* in_sizes, int n_in,
                              void* d_out, int out_size, void* d_ws, size_t ws_size,
                              hipStream_t stream) {
    const float* x   = (const float*)d_in[0];
    const float* W1  = (const float*)d_in[1];
    const float* g1  = (const float*)d_in[2];
    const float* b1  = (const float*)d_in[3];
    const float* W2  = (const float*)d_in[4];
    const float* g2  = (const float*)d_in[5];
    const float* b2  = (const float*)d_in[6];
    const float* W3  = (const float*)d_in[7];
    const float* g3  = (const float*)d_in[8];
    const float* b3  = (const float*)d_in[9];
    const float* W4  = (const float*)d_in[10];
    const float* g4  = (const float*)d_in[11];
    const float* b4  = (const float*)d_in[12];
    const float* W5  = (const float*)d_in[13];
    const float* g5  = (const float*)d_in[14];
    const float* b5  = (const float*)d_in[15];
    const float* L1  = (const float*)d_in[16];
    const float* g6  = (const float*)d_in[17];
    const float* b6  = (const float*)d_in[18];
    const float* L2  = (const float*)d_in[19];
    const float* bl2 = (const float*)d_in[20];
    const float* g7  = (const float*)d_in[21];
    const float* b7  = (const float*)d_in[22];
    const float* L3  = (const float*)d_in[23];
    const float* bl3 = (const float*)d_in[24];

    float* ws = (float*)d_ws;
    size_t off = 0;
    auto alloc = [&](size_t n) { size_t o = off; off += (n + 63) & ~(size_t)63; return o; };
    float* pd   = ws + alloc((size_t)NB * NPTS * NPTS);  // 134 MB, aliased with h5
    float* h5   = pd;
    float* xcT  = ws + alloc((size_t)RTOT * 640);
    float* hbuf = ws + alloc((size_t)RTOT * 128);
    float* xT   = ws + alloc((size_t)RTOT * 3);
    float* sumsA = ws + alloc(2048 * 5);
    float* feat = ws + alloc(RTOT);
    float* h1   = ws + alloc(32 * 512);
    float* h2   = ws + alloc(32 * 256);
    int*   idxb = (int*)(ws + alloc((size_t)RTOT * KNN));
    ushort* W5h = (ushort*)(ws + alloc(1024 * 640 / 2));
    ushort* W5l = (ushort*)(ws + alloc(1024 * 640 / 2));
    const float invR = 1.f / RTOT;

    k_prep<<<705, 256, 0, stream>>>(x, xT, W5, W5h, W5l, sumsA);

    auto run_knn = [&](const float* X, int ldx, int C) {
        if (C == 3)
            k_pd_sym<3><<<36 * NB, 256, 0, stream>>>(X, ldx, pd);
        else
            k_pd_sym<128><<<36 * NB, 256, 0, stream>>>(X, ldx, pd);
        k_topk_wave<<<RTOT / 8, 256, 0, stream>>>(pd, idxb);
    };
    auto run_conv = [&](const float* X, int ldx, int K, const float* W, int O, float* sums) {
        k_gemm_xwt<<<dim3(O / 64, RTOT / 64), 256, 0, stream>>>(X, ldx, K, W, hbuf, O);
        k_bn_stats<<<256, 256, 0, stream>>>(hbuf, O, O, RTOT, sums);
    };
    auto run_gf = [&](int C, int colOff, const float* sums, const float* g, const float* bta) {
        int ppb = 256 / C;
        k_graph_feature<<<RTOT / ppb, 256, 0, stream>>>(hbuf, C, C, idxb, sums, g, bta, invR,
                                                        xcT, 640, colOff);
    };

    // stage 1
    run_knn(xT, 3, 3);
    run_conv(xT, 3, 3, W1, 64, sumsA);
    run_gf(64, 0, sumsA, g1, b1);

    // stage 2
    run_knn(xcT + 0, 640, 128);
    run_conv(xcT + 0, 640, 128, W2, 64, sumsA + 2048);
    run_gf(64, 128, sumsA + 2048, g2, b2);

    // stage 3
    run_knn(xcT + 128, 640, 128);
    run_conv(xcT + 128, 640, 128, W3, 64, sumsA + 4096);
    run_gf(64, 256, sumsA + 4096, g3, b3);

    // stage 4
    run_knn(xcT + 256, 640, 128);
    run_conv(xcT + 256, 640, 128, W4, 128, sumsA + 6144);
    run_gf(128, 384, sumsA + 6144, g4, b4);

    // conv5 (BN stats fused) + chan-max (BN finalize fused)
    float* sums5 = sumsA + 8192;
    k_gemm5_mfma<<<1024, 512, 0, stream>>>(xcT, W5h, W5l, h5, sums5);
    k_chanmax<<<RTOT / 8, 256, 0, stream>>>(h5, sums5, g5, b5, invR, feat);

    // FC head
    k_fc_bn<<<64, 256, 0, stream>>>(feat, L1, nullptr, g6, b6, h1, 1024, 512);
    k_fc_bn<<<32, 256, 0, stream>>>(h1, L2, bl2, g7, b7, h2, 512, 256);
    k_fc<<<(32 * 40 + 255) / 256, 256, 0, stream>>>(h2, L3, bl3, (float*)d_out, 256, 40);
}